// Round 15
// baseline (445.896 us; speedup 1.0000x reference)
//
#include <hip/hip_runtime.h>
#include <math.h>

// DualStreamBlock: B=4, DIM=96, DIM3=288, H=W=64, L=4096, DSTATE=16
#define L 4096

typedef unsigned short u16;
typedef unsigned int u32;
typedef float f32x4 __attribute__((ext_vector_type(4)));
typedef short s16x8 __attribute__((ext_vector_type(8)));
typedef __attribute__((address_space(3))) unsigned int lds_u32;
typedef __attribute__((address_space(1))) unsigned int glb_u32;

__device__ __forceinline__ float softplus_f(float x) {
  return fmaxf(x, 0.f) + log1pf(__expf(-fabsf(x)));
}
__device__ __forceinline__ float silu_f(float x) {
  return x / (1.f + __expf(-x));
}
__device__ __forceinline__ float bf2f(u16 v) {
  return __uint_as_float(((unsigned)v) << 16);
}
__device__ __forceinline__ u16 f2bf(float f) {
  unsigned u = __float_as_uint(f);
  u += 0x7FFFu + ((u >> 16) & 1u);
  return (u16)(u >> 16);
}

// ---------------------------------------------------------------------------
// Weight convert: fp32 W[K][N] -> bf16 Wt[Npad][K] (transposed, zero-padded)
// ---------------------------------------------------------------------------
struct WSeg { const float* src; u16* dst; int K, N, Npad; };
struct WAll { WSeg s[8]; };

__global__ __launch_bounds__(256) void wconv_k(WAll wa) {
  const WSeg w = wa.s[blockIdx.z];
  const int nb = blockIdx.x * 32, kb = blockIdx.y * 32;
  if (nb >= w.Npad || kb >= w.K) return;
  __shared__ float t[32][33];
  const int tx = threadIdx.x & 31, ty = threadIdx.x >> 5;
  for (int r = ty; r < 32; r += 8) {
    int k = kb + r, n = nb + tx;
    t[r][tx] = (n < w.N) ? w.src[(size_t)k * w.N + n] : 0.f;
  }
  __syncthreads();
  for (int r = ty; r < 32; r += 8) {
    int n = nb + r;
    w.dst[(size_t)n * w.K + kb + tx] = f2bf(t[tx][r]);
  }
}

// ---------------------------------------------------------------------------
// Packed transpose prep: 4 segments x 512 blocks. chan-major fp32 -> token-major
// bf16. Per-segment: optional LN over C, optional +bias2[b*C+c].
// ---------------------------------------------------------------------------
struct TSeg { const float *x, *gam, *bet, *bias2; u16* out; int C, doLN; };
struct TPack { TSeg s[4]; };

__global__ __launch_bounds__(256) void trans_pack_k(TPack pk) {
  const TSeg t = pk.s[blockIdx.x >> 9];
  const int local = blockIdx.x & 511;
  const int C = t.C;
  __shared__ float tile[288][33];
  __shared__ float psum[8][32], psq[8][32];
  __shared__ float mm[32], rr[32];
  const int tid = threadIdx.x;
  const int l0 = (local & 127) * 32;
  const int b = local >> 7;
  const int lane32 = tid & 31, row8 = tid >> 5;
  const float* xb = t.x + (size_t)b * C * L + l0;

  for (int c = row8; c < C; c += 8)
    tile[c][lane32] = xb[(size_t)c * L + lane32];
  __syncthreads();

  if (t.doLN) {
    float s = 0.f, sq = 0.f;
    for (int c = row8; c < C; c += 8) {
      float v = tile[c][lane32];
      s += v; sq = fmaf(v, v, sq);
    }
    psum[row8][lane32] = s; psq[row8][lane32] = sq;
    __syncthreads();
    if (row8 == 0) {
      float ts = 0.f, tq = 0.f;
      #pragma unroll
      for (int g = 0; g < 8; ++g) { ts += psum[g][lane32]; tq += psq[g][lane32]; }
      float m = ts / C;
      float var = tq / C - m * m;
      mm[lane32] = m;
      rr[lane32] = rsqrtf(var + 1e-5f);
    }
    __syncthreads();
  }

  u16* ob = t.out + ((size_t)b * L + l0) * C;
  const int total = 32 * C;
  for (int o = tid * 8; o < total; o += 2048) {
    int tt = o / C, c = o % C;
    float m = 0.f, rs = 0.f;
    if (t.doLN) { m = mm[tt]; rs = rr[tt]; }
    union { u16 u[8]; int4 v; } pkv;
    #pragma unroll
    for (int j = 0; j < 8; ++j) {
      float v = tile[c + j][tt];
      if (t.doLN) v = (v - m) * rs * t.gam[c + j] + t.bet[c + j];
      else if (t.bias2) v += t.bias2[b * C + c + j];
      pkv.u[j] = f2bf(v);
    }
    *(int4*)(ob + o) = pkv.v;
  }
}

// ---------------------------------------------------------------------------
// Packed causal depthwise conv k=4 + bias + silu, token-major bf16 (2 segments)
// ---------------------------------------------------------------------------
struct CSeg { const u16* x; const float* w; const float* b; u16* y; int C, nbx; };
struct CPack { CSeg s[2]; int start1; };

__global__ __launch_bounds__(256) void conv_pack_k(CPack pk) {
  const int bid = blockIdx.x;
  const int si = bid >= pk.start1;
  const CSeg q = pk.s[si];
  const int local = si ? bid - pk.start1 : bid;
  const int C = q.C;
  const int c = (local % q.nbx) * 64 + (threadIdx.x & 63);
  const int chunk = (local / q.nbx) * 4 + (threadIdx.x >> 6);
  const int T0 = chunk * 8;
  const float w0 = q.w[c * 4], w1 = q.w[c * 4 + 1], w2 = q.w[c * 4 + 2], w3 = q.w[c * 4 + 3];
  const float bs = q.b[c];
  const bool first = (T0 & (L - 1)) == 0;
  float v[11];
  #pragma unroll
  for (int i = 0; i < 11; ++i) {
    if (i < 3 && first) v[i] = 0.f;
    else v[i] = bf2f(q.x[(size_t)(T0 - 3 + i) * C + c]);
  }
  #pragma unroll
  for (int j = 0; j < 8; ++j) {
    float s = bs + w0 * v[j] + w1 * v[j + 1] + w2 * v[j + 2] + w3 * v[j + 3];
    q.y[(size_t)(T0 + j) * C + c] = f2bf(silu_f(s));
  }
}

// ---------------------------------------------------------------------------
// Packed MFMA bf16 GEMM (up to 4 segments). Tile 128x128, 4 waves (2x2), BK=32,
// 2-stage double-buffer (32KB LDS), global_load_lds, per-segment XCD swizzle.
// bf16 epilogues (1,3,4,5) route through a 32KB XOR-swizzled LDS C-tile and
// store coalesced int4 rows.
// epi: 0 fp32 row-major; 1 bf16 row-major; 2 chan-major fp32 + residual;
//      3 silu(x+bias) bf16; 4 (x+bias) bf16; 5 split bf16 (outB0|outB1).
// ---------------------------------------------------------------------------
struct MSeg {
  const u16 *A0, *A1, *Wt;
  const float *bias, *res;
  float* outF; u16 *outB0, *outB1;
  int K, K1, Nout, ldA, ldo, split, nbx, nwg, epi;
};
struct MPack { MSeg s[4]; int starts[4]; int nseg; };

__global__ __launch_bounds__(256) void mfma_pack_k(MPack pk) {
  const int bid = blockIdx.x;
  int si = 0;
  #pragma unroll
  for (int k = 1; k < 4; ++k)
    if (k < pk.nseg && bid >= pk.starts[k]) si = k;
  const MSeg p = pk.s[si];
  const int wg = bid - pk.starts[si];

  __shared__ u16 lds[16384];            // As[2][4096] | Bs[2][4096]; reused as C-tile
  u16* As0 = lds;
  u16* Bs0 = lds + 8192;
  const int tid = threadIdx.x;
  const int lane = tid & 63;
  const int wid = tid >> 6;
  const int wm = wid >> 1, wn = wid & 1;
  const int newid = (wg & 7) * (p.nwg >> 3) + (wg >> 3);
  const int n0 = (newid % p.nbx) * 128;
  const int m0 = (newid / p.nbx) * 128;
  const int srow = tid & 127;
  const int skc = tid >> 7;
  const int kgrp = lane >> 4, l16 = lane & 15;

  f32x4 acc[4][4];
  #pragma unroll
  for (int i = 0; i < 4; ++i)
    #pragma unroll
    for (int j = 0; j < 4; ++j)
      acc[i][j] = (f32x4){0.f, 0.f, 0.f, 0.f};

  auto stage = [&](int bi, int k0) {
    const u16* Ab = p.A0;
    int kc = k0;
    if (p.A1 && k0 >= p.K1) { Ab = p.A1; kc = k0 - p.K1; }
    const u16* g0 = Ab + (size_t)(m0 + srow) * p.ldA + kc + skc * 8;
    u16* Ad = As0 + bi * 4096;
    __builtin_amdgcn_global_load_lds((const glb_u32*)g0,
        (lds_u32*)(Ad + wid * 512), 16, 0, 0);
    __builtin_amdgcn_global_load_lds((const glb_u32*)(g0 + 16),
        (lds_u32*)(Ad + 2048 + wid * 512), 16, 0, 0);
    const u16* h0 = p.Wt + (size_t)(n0 + srow) * p.K + k0 + skc * 8;
    u16* Bd = Bs0 + bi * 4096;
    __builtin_amdgcn_global_load_lds((const glb_u32*)h0,
        (lds_u32*)(Bd + wid * 512), 16, 0, 0);
    __builtin_amdgcn_global_load_lds((const glb_u32*)(h0 + 16),
        (lds_u32*)(Bd + 2048 + wid * 512), 16, 0, 0);
  };

  const int nt = p.K >> 5;
  stage(0, 0);
  __syncthreads();
  for (int t = 0; t < nt; ++t) {
    const int cur = t & 1;
    if (t + 1 < nt) stage(cur ^ 1, (t + 1) << 5);
    s16x8 af[4], bfr[4];
    #pragma unroll
    for (int mi = 0; mi < 4; ++mi)
      af[mi] = *(const s16x8*)(As0 + cur * 4096 + kgrp * 1024 + (wm * 64 + mi * 16 + l16) * 8);
    #pragma unroll
    for (int ni = 0; ni < 4; ++ni)
      bfr[ni] = *(const s16x8*)(Bs0 + cur * 4096 + kgrp * 1024 + (wn * 64 + ni * 16 + l16) * 8);
    #pragma unroll
    for (int mi = 0; mi < 4; ++mi)
      #pragma unroll
      for (int ni = 0; ni < 4; ++ni)
        acc[mi][ni] = __builtin_amdgcn_mfma_f32_16x16x32_bf16(af[mi], bfr[ni], acc[mi][ni], 0, 0, 0);
    if (t + 1 < nt) __syncthreads();
  }

  if (p.epi == 0) {
    #pragma unroll
    for (int mi = 0; mi < 4; ++mi) {
      #pragma unroll
      for (int j = 0; j < 4; ++j) {
        int token = m0 + wm * 64 + mi * 16 + (lane >> 4) * 4 + j;
        #pragma unroll
        for (int ni = 0; ni < 4; ++ni) {
          int n = n0 + wn * 64 + ni * 16 + l16;
          if (n < p.Nout) p.outF[(size_t)token * p.ldo + n] = acc[mi][ni][j];
        }
      }
    }
  } else if (p.epi == 2) {
    #pragma unroll
    for (int mi = 0; mi < 4; ++mi) {
      int token = m0 + wm * 64 + mi * 16 + (lane >> 4) * 4;
      int b = token >> 12, l = token & (L - 1);
      #pragma unroll
      for (int ni = 0; ni < 4; ++ni) {
        int n = n0 + wn * 64 + ni * 16 + l16;
        if (n < p.Nout) {
          size_t o = ((size_t)b * p.Nout + n) * L + l;
          float4 r = *(const float4*)(p.res + o);
          float4 v = make_float4(acc[mi][ni][0] + r.x, acc[mi][ni][1] + r.y,
                                 acc[mi][ni][2] + r.z, acc[mi][ni][3] + r.w);
          *(float4*)(p.outF + o) = v;
        }
      }
    }
  } else {
    // bf16 epis (1,3,4,5): stage C through XOR-swizzled LDS, coalesced stores
    __syncthreads();   // all waves done with As/Bs
    #pragma unroll
    for (int mi = 0; mi < 4; ++mi) {
      #pragma unroll
      for (int j = 0; j < 4; ++j) {
        int tok = wm * 64 + mi * 16 + (lane >> 4) * 4 + j;
        #pragma unroll
        for (int ni = 0; ni < 4; ++ni) {
          int nl = wn * 64 + ni * 16 + l16;
          int n = n0 + nl;
          float v = acc[mi][ni][j];
          if (n < p.Nout && (p.epi == 3 || p.epi == 4)) {
            v += p.bias[n];
            if (p.epi == 3) v = silu_f(v);
          }
          lds[tok * 128 + ((((nl >> 4) ^ (tok & 7))) << 4) + (nl & 15)] = f2bf(v);
        }
      }
    }
    __syncthreads();
    #pragma unroll
    for (int it = 0; it < 8; ++it) {
      int idx = it * 256 + tid;
      int row = idx >> 4, c16 = idx & 15;
      int nl0 = c16 * 8;
      if (n0 + nl0 < p.Nout) {
        int g = nl0 >> 4;
        int4 vv = *(const int4*)(lds + row * 128 + ((g ^ (row & 7)) << 4) + (nl0 & 15));
        int token = m0 + row;
        if (p.epi == 5) {
          int n = n0 + nl0;
          if (n < p.split) *(int4*)(p.outB0 + (size_t)token * p.split + n) = vv;
          else *(int4*)(p.outB1 + (size_t)token * p.split + (n - p.split)) = vv;
        } else {
          *(int4*)(p.outB0 + (size_t)token * p.ldo + n0 + nl0) = vv;
        }
      }
    }
  }
}

// ---------------------------------------------------------------------------
// Packed chunked selective scan v7: block = one (b, chunk, 192-channel slice).
// 256 threads stage xdbl's dt columns AND B[/C] columns into LDS once; the
// dt-projection + softplus is computed per-thread with 1-token LOOKAHEAD
// (independent FMAs, off the h critical path) -- the separate fp32 dt-GEMM
// dispatch and the dlt buffers are DELETED. Per-token global loads: 2 (u, z).
// Fast decay path: log-depth power tree. PV: 4 partial accumulators.
// PF layout [c][slot 0..31][NCH]: slots 0..15 = P, 16..31 = F/Hin.
// ---------------------------------------------------------------------------
struct S3Seg {
  const u16* u; const float* Alog; const float* xdbl;
  const float* dtw; const float* dtb;
  const float* Dp; const u16* zT; float* PF; u16* yT;
  int rdim, Dch, CLen, NCH, nsl;
};
struct S3Pack { S3Seg s[2]; int start1; };

template<int PASS>
__global__ __launch_bounds__(256) void scan3_pack_k(S3Pack pk) {
  __shared__ float rows_bc[64][32];   // B | C (aligned for f32x4 reads)
  __shared__ float rows_dt[64][18];   // dt inputs (cols 0..17 of xdbl)
  const int bid = blockIdx.x;
  const int si = bid >= pk.start1;
  const S3Seg q = pk.s[si];
  const int local = si ? bid - pk.start1 : bid;
  const int nsl = q.nsl;
  const int NC = L / q.CLen;
  const int slice = local % nsl;
  const int c = (local / nsl) % NC;
  const int b = local / (nsl * NC);
  const int tid = threadIdx.x;
  const size_t tok0 = (size_t)b * L + (size_t)c * q.CLen;

  // cooperative stage: B cols (pass1) or B+C cols (pass3)
  {
    const int W2 = (PASS == 1) ? 8 : 16;     // float2 count per row
    const int tot2 = q.CLen * W2;
    for (int i = tid; i < tot2; i += 256) {
      int r = i / W2, j = i - r * W2;
      float2 v = *(const float2*)(q.xdbl + (tok0 + r) * 64 + q.rdim + 2 * j);
      *(float2*)&rows_bc[r][2 * j] = v;
    }
    // dt input cols 0..17 (always 9 float2; cols >= rdim are B-data, masked by wc=0)
    const int totd = q.CLen * 9;
    for (int i = tid; i < totd; i += 256) {
      int r = i / 9, j = i - r * 9;
      float2 v = *(const float2*)(q.xdbl + (tok0 + r) * 64 + 2 * j);
      *(float2*)&rows_dt[r][2 * j] = v;
    }
  }
  __syncthreads();

  if (tid < 192) {
    const int d = slice * 192 + tid;
    const int Dch = q.Dch;
    float An[16], h[16];
    #pragma unroll
    for (int n = 0; n < 16; ++n) {
      An[n] = -__expf(q.Alog[d * 16 + n]);
      h[n] = 0.f;
    }
    bool fast = true;
    #pragma unroll
    for (int n = 1; n < 16; ++n) {
      float ref = (float)(n + 1) * An[0];
      if (fabsf(An[n] - ref) > 1e-4f * fabsf(ref)) fast = false;
    }
    // dt-projection weights, zero-padded to 18
    float wc[18];
    #pragma unroll
    for (int k = 0; k < 18; ++k)
      wc[k] = (k < q.rdim) ? q.dtw[k * Dch + d] : 0.f;
    const float db = q.dtb[d];

    const int ch = b * Dch + d;
    if (PASS == 3) {
      #pragma unroll
      for (int n = 0; n < 16; ++n)
        h[n] = q.PF[((size_t)c * 32 + 16 + n) * q.NCH + ch];
    }
    const float Dd = q.Dp[d];
    const u16* up = q.u + tok0 * Dch + d;
    const u16* zp = q.zT + tok0 * Dch + d;
    u16* yr = q.yT + tok0 * Dch + d;
    float S = 0.f;

    auto dlt_at = [&](int t) {
      float a0 = db, a1 = 0.f;
      #pragma unroll
      for (int k = 0; k < 9; ++k) {
        a0 = fmaf(rows_dt[t][2 * k], wc[2 * k], a0);
        a1 = fmaf(rows_dt[t][2 * k + 1], wc[2 * k + 1], a1);
      }
      return softplus_f(a0 + a1);
    };

    // 1-token lookahead (dl projection + u/z loads off the critical path)
    float dl_n = dlt_at(0);
    float uu_n = bf2f(up[0]);
    float zv_n = (PASS == 3) ? bf2f(zp[0]) : 0.f;

    #define SCAN_BODY(FAST)                                                    \
    for (int t = 0; t < q.CLen; ++t) {                                         \
      float dl = dl_n, uu = uu_n, zv = zv_n;                                   \
      if (t + 1 < q.CLen) {                                                    \
        const size_t on = (size_t)(t + 1) * Dch;                               \
        dl_n = dlt_at(t + 1);                                                  \
        uu_n = bf2f(up[on]);                                                   \
        if (PASS == 3) zv_n = bf2f(zp[on]);                                    \
      }                                                                        \
      float w = dl * uu;                                                       \
      f32x4 B4[4];                                                             \
      _Pragma("unroll")                                                        \
      for (int g = 0; g < 4; ++g) B4[g] = *(const f32x4*)&rows_bc[t][4 * g];   \
      if (PASS == 1) S += dl;                                                  \
      if (FAST) {                                                              \
        float a = __expf(dl * An[0]);                                          \
        float e[16];                                                           \
        e[0] = a;                                                              \
        e[1] = a * a;                                                          \
        e[2] = e[1] * e[0];                                                    \
        e[3] = e[1] * e[1];                                                    \
        e[4] = e[3] * e[0]; e[5] = e[3] * e[1];                                \
        e[6] = e[3] * e[2]; e[7] = e[3] * e[3];                                \
        _Pragma("unroll")                                                      \
        for (int j2 = 0; j2 < 8; ++j2) e[8 + j2] = e[7] * e[j2];               \
        _Pragma("unroll")                                                      \
        for (int n = 0; n < 16; ++n)                                           \
          h[n] = fmaf(e[n], h[n], w * B4[n >> 2][n & 3]);                      \
      } else {                                                                 \
        _Pragma("unroll")                                                      \
        for (int n = 0; n < 16; ++n)                                           \
          h[n] = fmaf(__expf(dl * An[n]), h[n], w * B4[n >> 2][n & 3]);        \
      }                                                                        \
      if (PASS == 3) {                                                         \
        f32x4 C4[4];                                                           \
        _Pragma("unroll")                                                      \
        for (int g = 0; g < 4; ++g) C4[g] = *(const f32x4*)&rows_bc[t][16 + 4 * g]; \
        float y0 = 0.f, y1 = 0.f, y2 = 0.f, y3 = 0.f;                          \
        _Pragma("unroll")                                                      \
        for (int k2 = 0; k2 < 4; ++k2) {                                       \
          y0 = fmaf(h[k2],      C4[0][k2], y0);                                \
          y1 = fmaf(h[4 + k2],  C4[1][k2], y1);                                \
          y2 = fmaf(h[8 + k2],  C4[2][k2], y2);                                \
          y3 = fmaf(h[12 + k2], C4[3][k2], y3);                                \
        }                                                                      \
        float y = (y0 + y1) + (y2 + y3);                                       \
        yr[(size_t)t * Dch] = f2bf((y + Dd * uu) * silu_f(zv));                \
      }                                                                        \
    }

    if (fast) { SCAN_BODY(1) } else { SCAN_BODY(0) }
    #undef SCAN_BODY

    if (PASS == 1) {
      #pragma unroll
      for (int n = 0; n < 16; ++n) {
        q.PF[((size_t)c * 32 + n) * q.NCH + ch] = __expf(An[n] * S);
        q.PF[((size_t)c * 32 + 16 + n) * q.NCH + ch] = h[n];
      }
    }
  }
}

// Packed stitch: per (ch, state) sequential over chunks; rewrites F with Hin.
__global__ __launch_bounds__(256) void stitch_pack_k(
    float* PF0, int NC0, int NCH0, int tot0,
    float* PF1, int NC1, int NCH1, int tot1) {
  int idx = blockIdx.x * 256 + threadIdx.x;
  float* PF; int NC, NCH;
  if (idx < tot0) { PF = PF0; NC = NC0; NCH = NCH0; }
  else { idx -= tot0; if (idx >= tot1) return; PF = PF1; NC = NC1; NCH = NCH1; }
  int ch = idx % NCH, n = idx / NCH;
  float hin = 0.f;
  for (int c = 0; c < NC; ++c) {
    float* Ps = PF + ((size_t)c * 32 + n) * NCH + ch;
    float* Fs = PF + ((size_t)c * 32 + 16 + n) * NCH + ch;
    float Pv = *Ps, Fv = *Fs;
    *Fs = hin;
    hin = fmaf(Pv, hin, Fv);
  }
}

// ---------------------------------------------------------------------------
extern "C" void kernel_launch(void* const* d_in, const int* in_sizes, int n_in,
                              void* d_out, int out_size, void* d_ws, size_t ws_size,
                              hipStream_t stream) {
  const float* m_ll    = (const float*)d_in[0];
  const float* m_high  = (const float*)d_in[1];
  const float* zanc    = (const float*)d_in[2];
  const float* Kin     = (const float*)d_in[3];
  const float* Qin     = (const float*)d_in[4];
  const float* s_in_w  = (const float*)d_in[5];
  const float* s_conv_w= (const float*)d_in[6];
  const float* s_conv_b= (const float*)d_in[7];
  const float* s_x_w   = (const float*)d_in[8];
  const float* s_dt_w  = (const float*)d_in[9];
  const float* s_dt_b  = (const float*)d_in[10];
  const float* s_Alog  = (const float*)d_in[11];
  const float* s_D     = (const float*)d_in[12];
  const float* s_out_w = (const float*)d_in[13];
  const float* t_in_w  = (const float*)d_in[14];
  const float* t_conv_w= (const float*)d_in[15];
  const float* t_conv_b= (const float*)d_in[16];
  const float* t_kln_g = (const float*)d_in[17];
  const float* t_kln_b = (const float*)d_in[18];
  const float* t_k_w   = (const float*)d_in[19];
  const float* t_k_b   = (const float*)d_in[20];
  const float* t_qln_g = (const float*)d_in[21];
  const float* t_qln_b = (const float*)d_in[22];
  const float* t_q_w   = (const float*)d_in[23];
  const float* t_q_b   = (const float*)d_in[24];
  const float* t_dtbc_w= (const float*)d_in[25];
  const float* t_dt_w  = (const float*)d_in[26];
  const float* t_dt_b  = (const float*)d_in[27];
  const float* t_gate_w= (const float*)d_in[28];
  const float* t_gate_b= (const float*)d_in[29];
  const float* t_Alog  = (const float*)d_in[30];
  const float* t_D     = (const float*)d_in[31];
  const float* t_out_w = (const float*)d_in[32];

  float* out1 = (float*)d_out;               // (4, 96, 4096)
  float* out2 = out1 + (size_t)4 * 96 * L;   // (4, 288, 4096) = 4,718,592 f
  float* ws = (float*)d_ws;

  // Weights (bf16) — sizes in float units = (u16 count)/2
  u16* w_sin   = (u16*)(ws + 0);        // [384][96]   = 18,432 f
  u16* w_sx    = (u16*)(ws + 18432);    // [128][192]  = 12,288 f
  u16* w_sout  = (u16*)(ws + 30720);    // [128][192]  = 12,288 f
  u16* w_tin   = (u16*)(ws + 43008);    // [640][288]  = 92,160 f
  u16* w_tk    = (u16*)(ws + 135168);   // [640][288]
  u16* w_tq    = (u16*)(ws + 227328);   // [640][288]
  u16* w_tdtbc = (u16*)(ws + 319488);   // [128][1152] = 73,728 f
  u16* w_tgate = (u16*)(ws + 393216);   // [640][1152] = 368,640 f
  u16* w_tout  = (u16*)(ws + 761856);   // [384][576]  = 110,592 f -> ends 872,448

  // Activations (u16 [16384][C] = 8192*C floats)
  float* B_ahi  = ws + 872448;    // u16[16384][288] = 2,359,296 f -> 3,231,744
  float* B_aK   = ws + 3231744;   // -> 5,591,040
  float* B_aQ   = ws + 5591040;   // -> 7,950,336
  float* B_all  = ws + 7950336;   // u16[16384][96] = 786,432 f -> 8,736,768
  float* B_xin  = ws + 8736768;   // u16[16384][192] = 1,572,864 f -> 10,309,632
  float* B_zTs  = ws + 10309632;  // -> 11,882,496
  float* B_xc   = ws + 11882496;  // -> 13,455,360
  float* B_xin3 = ws + 13455360;  // u16[16384][576] = 4,718,592 f -> 18,173,952
  float* B_xc3  = ws + 18173952;  // -> 22,892,544
  float* B_kp   = ws + 22892544;  // -> 27,611,136
  float* B_qp   = ws + 27611136;  // -> 32,329,728
  float* B_zg3  = ws + 32329728;  // -> 37,048,320
  float* B_xdbl = ws + 37048320;  // fp32 [16384][64] -> 38,096,896
  float* B_xdbl3= ws + 38096896;  // -> 39,145,472
  float* B_PFs  = ws + 39145472;  // fp32 128*32*768 -> 42,291,200
  // Overlays (liveness-verified):
  u16* y_bf = (u16*)B_xin;        // over x_in (dead after conv)
  u16* y3   = (u16*)B_xin3;       // over xin3 (dead after conv)
  float* PFt = out2;              // 64*32*2304 == |out2| (dead until P3)

  dim3 blk(256);

  // 1) weight conversion
  {
    WAll wa;
    wa.s[0] = {s_in_w,   w_sin,    96, 384, 384};
    wa.s[1] = {s_x_w,    w_sx,    192,  38, 128};
    wa.s[2] = {s_out_w,  w_sout,  192,  96, 128};
    wa.s[3] = {t_in_w,   w_tin,   288, 576, 640};
    wa.s[4] = {t_k_w,    w_tk,    288, 576, 640};
    wa.s[5] = {t_q_w,    w_tq,    288, 576, 640};
    wa.s[6] = {t_dtbc_w, w_tdtbc, 1152, 50, 128};
    wa.s[7] = {t_gate_w, w_tgate, 1152, 576, 640};
    wconv_k<<<dim3(20, 36, 8), blk, 0, stream>>>(wa);
    WAll wb;
    wb.s[0] = {t_out_w,  w_tout,  576, 288, 384};
    wconv_k<<<dim3(12, 18, 1), blk, 0, stream>>>(wb);
  }

  // 2) all four transpose-preps (4 x 512 blocks)
  {
    TPack tp{};
    tp.s[0] = {m_ll,   nullptr, nullptr, zanc,    (u16*)B_all, 96,  0};
    tp.s[1] = {m_high, nullptr, nullptr, nullptr, (u16*)B_ahi, 288, 0};
    tp.s[2] = {Kin,    t_kln_g, t_kln_b, nullptr, (u16*)B_aK,  288, 1};
    tp.s[3] = {Qin,    t_qln_g, t_qln_b, nullptr, (u16*)B_aQ,  288, 1};
    trans_pack_k<<<dim3(2048), blk, 0, stream>>>(tp);
  }

  // 3) P1: s_in + t_in + t_k + t_q (2304 blocks, 128^2 tiles)
  {
    MPack pk{}; pk.nseg = 4;
    pk.starts[0] = 0; pk.starts[1] = 384; pk.starts[2] = 1024; pk.starts[3] = 1664;
    MSeg a{}; a.A0 = (u16*)B_all; a.Wt = w_sin; a.K = 96; a.K1 = 1 << 28; a.Nout = 384;
    a.ldA = 96; a.split = 192; a.outB0 = (u16*)B_xin; a.outB1 = (u16*)B_zTs;
    a.nbx = 3; a.nwg = 384; a.epi = 5; pk.s[0] = a;
    MSeg b{}; b.A0 = (u16*)B_ahi; b.Wt = w_tin; b.K = 288; b.K1 = 1 << 28; b.Nout = 576;
    b.ldA = 288; b.ldo = 576; b.outB0 = (u16*)B_xin3; b.nbx = 5; b.nwg = 640; b.epi = 1; pk.s[1] = b;
    MSeg c{}; c.A0 = (u16*)B_aK; c.Wt = w_tk; c.K = 288; c.K1 = 1 << 28; c.Nout = 576;
    c.ldA = 288; c.ldo = 576; c.bias = t_k_b; c.outB0 = (u16*)B_kp; c.nbx = 5; c.nwg = 640; c.epi = 3; pk.s[2] = c;
    MSeg d{}; d.A0 = (u16*)B_aQ; d.Wt = w_tq; d.K = 288; d.K1 = 1 << 28; d.Nout = 576;
    d.ldA = 288; d.ldo = 576; d.bias = t_q_b; d.outB0 = (u16*)B_qp; d.nbx = 5; d.nwg = 640; d.epi = 3; pk.s[3] = d;
    mfma_pack_k<<<dim3(2304), blk, 0, stream>>>(pk);
  }

  // 4) both convs (1536 + 4608 blocks)
  {
    CPack cp{}; cp.start1 = 1536;
    cp.s[0] = {(u16*)B_xin,  s_conv_w, s_conv_b, (u16*)B_xc,  192, 3};
    cp.s[1] = {(u16*)B_xin3, t_conv_w, t_conv_b, (u16*)B_xc3, 576, 9};
    conv_pack_k<<<dim3(6144), blk, 0, stream>>>(cp);
  }

  // 5) P2: s_x + dtbc + gate (128 + 128 + 640 = 896 blocks)
  {
    MPack pk{}; pk.nseg = 3;
    pk.starts[0] = 0; pk.starts[1] = 128; pk.starts[2] = 256; pk.starts[3] = 896;
    MSeg a{}; a.A0 = (u16*)B_xc; a.Wt = w_sx; a.K = 192; a.K1 = 1 << 28; a.Nout = 64;
    a.ldA = 192; a.ldo = 64; a.outF = B_xdbl; a.nbx = 1; a.nwg = 128; a.epi = 0; pk.s[0] = a;
    MSeg b{}; b.A0 = (u16*)B_xc3; b.A1 = (u16*)B_kp; b.Wt = w_tdtbc; b.K = 1152; b.K1 = 576;
    b.Nout = 64; b.ldA = 576; b.ldo = 64; b.outF = B_xdbl3; b.nbx = 1; b.nwg = 128; b.epi = 0; pk.s[1] = b;
    MSeg c{}; c.A0 = (u16*)B_xc3; c.A1 = (u16*)B_qp; c.Wt = w_tgate; c.K = 1152; c.K1 = 576;
    c.Nout = 576; c.ldA = 576; c.ldo = 576; c.bias = t_gate_b; c.outB0 = (u16*)B_zg3;
    c.nbx = 5; c.nwg = 640; c.epi = 4; pk.s[2] = c;
    mfma_pack_k<<<dim3(896), blk, 0, stream>>>(pk);
  }

  // 6-8) scans (dt-projection fused into the PARALLEL staging/lookahead phase;
  //       the separate fp32 dt-GEMM dispatch is deleted) + stitch
  S3Pack sp{}; sp.start1 = 512;
  sp.s[0] = {(u16*)B_xc,  s_Alog, B_xdbl,  s_dt_w, s_dt_b, s_D, (u16*)B_zTs, B_PFs, y_bf, 6,  192, 32, 768,  1};
  sp.s[1] = {(u16*)B_xc3, t_Alog, B_xdbl3, t_dt_w, t_dt_b, t_D, (u16*)B_zg3, PFt,   y3,   18, 576, 64, 2304, 3};
  scan3_pack_k<1><<<dim3(1280), blk, 0, stream>>>(sp);
  stitch_pack_k<<<dim3(192), blk, 0, stream>>>(B_PFs, 128, 768, 12288, PFt, 64, 2304, 36864);
  scan3_pack_k<3><<<dim3(1280), blk, 0, stream>>>(sp);

  // 9) P3: s_out + t_out (128 + 384 = 512 blocks)
  {
    MPack pk{}; pk.nseg = 2;
    pk.starts[0] = 0; pk.starts[1] = 128; pk.starts[2] = 512; pk.starts[3] = 512;
    MSeg a{}; a.A0 = y_bf; a.Wt = w_sout; a.K = 192; a.K1 = 1 << 28; a.Nout = 96;
    a.ldA = 192; a.res = m_ll; a.outF = out1; a.nbx = 1; a.nwg = 128; a.epi = 2; pk.s[0] = a;
    MSeg b{}; b.A0 = y3; b.Wt = w_tout; b.K = 576; b.K1 = 1 << 28; b.Nout = 288;
    b.ldA = 576; b.res = m_high; b.outF = out2; b.nbx = 3; b.nwg = 384; b.epi = 2; pk.s[1] = b;
    mfma_pack_k<<<dim3(512), blk, 0, stream>>>(pk);
  }
}

// Round 16
// 397.383 us; speedup vs baseline: 1.1221x; 1.1221x over previous
//
#include <hip/hip_runtime.h>
#include <math.h>

// DualStreamBlock: B=4, DIM=96, DIM3=288, H=W=64, L=4096, DSTATE=16
#define L 4096

typedef unsigned short u16;
typedef unsigned int u32;
typedef float f32x4 __attribute__((ext_vector_type(4)));
typedef short s16x8 __attribute__((ext_vector_type(8)));
typedef __attribute__((address_space(3))) unsigned int lds_u32;
typedef __attribute__((address_space(1))) unsigned int glb_u32;

__device__ __forceinline__ float softplus_f(float x) {
  return fmaxf(x, 0.f) + log1pf(__expf(-fabsf(x)));
}
__device__ __forceinline__ float silu_f(float x) {
  return x / (1.f + __expf(-x));
}
__device__ __forceinline__ float bf2f(u16 v) {
  return __uint_as_float(((unsigned)v) << 16);
}
__device__ __forceinline__ u16 f2bf(float f) {
  unsigned u = __float_as_uint(f);
  u += 0x7FFFu + ((u >> 16) & 1u);
  return (u16)(u >> 16);
}

// ---------------------------------------------------------------------------
// Weight convert: fp32 W[K][N] -> bf16 Wt[Npad][K] (transposed, zero-padded)
// ---------------------------------------------------------------------------
struct WSeg { const float* src; u16* dst; int K, N, Npad; };
struct WAll { WSeg s[8]; };

__global__ __launch_bounds__(256) void wconv_k(WAll wa) {
  const WSeg w = wa.s[blockIdx.z];
  const int nb = blockIdx.x * 32, kb = blockIdx.y * 32;
  if (nb >= w.Npad || kb >= w.K) return;
  __shared__ float t[32][33];
  const int tx = threadIdx.x & 31, ty = threadIdx.x >> 5;
  for (int r = ty; r < 32; r += 8) {
    int k = kb + r, n = nb + tx;
    t[r][tx] = (n < w.N) ? w.src[(size_t)k * w.N + n] : 0.f;
  }
  __syncthreads();
  for (int r = ty; r < 32; r += 8) {
    int n = nb + r;
    w.dst[(size_t)n * w.K + kb + tx] = f2bf(t[tx][r]);
  }
}

// ---------------------------------------------------------------------------
// Packed transpose prep: 4 segments x 512 blocks. chan-major fp32 -> token-major
// bf16. Per-segment: optional LN over C, optional +bias2[b*C+c].
// ---------------------------------------------------------------------------
struct TSeg { const float *x, *gam, *bet, *bias2; u16* out; int C, doLN; };
struct TPack { TSeg s[4]; };

__global__ __launch_bounds__(256) void trans_pack_k(TPack pk) {
  const TSeg t = pk.s[blockIdx.x >> 9];
  const int local = blockIdx.x & 511;
  const int C = t.C;
  __shared__ float tile[288][33];
  __shared__ float psum[8][32], psq[8][32];
  __shared__ float mm[32], rr[32];
  const int tid = threadIdx.x;
  const int l0 = (local & 127) * 32;
  const int b = local >> 7;
  const int lane32 = tid & 31, row8 = tid >> 5;
  const float* xb = t.x + (size_t)b * C * L + l0;

  for (int c = row8; c < C; c += 8)
    tile[c][lane32] = xb[(size_t)c * L + lane32];
  __syncthreads();

  if (t.doLN) {
    float s = 0.f, sq = 0.f;
    for (int c = row8; c < C; c += 8) {
      float v = tile[c][lane32];
      s += v; sq = fmaf(v, v, sq);
    }
    psum[row8][lane32] = s; psq[row8][lane32] = sq;
    __syncthreads();
    if (row8 == 0) {
      float ts = 0.f, tq = 0.f;
      #pragma unroll
      for (int g = 0; g < 8; ++g) { ts += psum[g][lane32]; tq += psq[g][lane32]; }
      float m = ts / C;
      float var = tq / C - m * m;
      mm[lane32] = m;
      rr[lane32] = rsqrtf(var + 1e-5f);
    }
    __syncthreads();
  }

  u16* ob = t.out + ((size_t)b * L + l0) * C;
  const int total = 32 * C;
  for (int o = tid * 8; o < total; o += 2048) {
    int tt = o / C, c = o % C;
    float m = 0.f, rs = 0.f;
    if (t.doLN) { m = mm[tt]; rs = rr[tt]; }
    union { u16 u[8]; int4 v; } pkv;
    #pragma unroll
    for (int j = 0; j < 8; ++j) {
      float v = tile[c + j][tt];
      if (t.doLN) v = (v - m) * rs * t.gam[c + j] + t.bet[c + j];
      else if (t.bias2) v += t.bias2[b * C + c + j];
      pkv.u[j] = f2bf(v);
    }
    *(int4*)(ob + o) = pkv.v;
  }
}

// ---------------------------------------------------------------------------
// Packed causal depthwise conv k=4 + bias + silu, token-major bf16 (2 segments)
// ---------------------------------------------------------------------------
struct CSeg { const u16* x; const float* w; const float* b; u16* y; int C, nbx; };
struct CPack { CSeg s[2]; int start1; };

__global__ __launch_bounds__(256) void conv_pack_k(CPack pk) {
  const int bid = blockIdx.x;
  const int si = bid >= pk.start1;
  const CSeg q = pk.s[si];
  const int local = si ? bid - pk.start1 : bid;
  const int C = q.C;
  const int c = (local % q.nbx) * 64 + (threadIdx.x & 63);
  const int chunk = (local / q.nbx) * 4 + (threadIdx.x >> 6);
  const int T0 = chunk * 8;
  const float w0 = q.w[c * 4], w1 = q.w[c * 4 + 1], w2 = q.w[c * 4 + 2], w3 = q.w[c * 4 + 3];
  const float bs = q.b[c];
  const bool first = (T0 & (L - 1)) == 0;
  float v[11];
  #pragma unroll
  for (int i = 0; i < 11; ++i) {
    if (i < 3 && first) v[i] = 0.f;
    else v[i] = bf2f(q.x[(size_t)(T0 - 3 + i) * C + c]);
  }
  #pragma unroll
  for (int j = 0; j < 8; ++j) {
    float s = bs + w0 * v[j] + w1 * v[j + 1] + w2 * v[j + 2] + w3 * v[j + 3];
    q.y[(size_t)(T0 + j) * C + c] = f2bf(silu_f(s));
  }
}

// ---------------------------------------------------------------------------
// Packed MFMA bf16 GEMM (up to 4 segments). Tile 128x128, 4 waves (2x2), BK=32,
// 2-stage double-buffer (32KB LDS), global_load_lds, per-segment XCD swizzle.
// bf16 epilogues (1,3,4,5) route through a 32KB XOR-swizzled LDS C-tile and
// store coalesced int4 rows.
// epi: 0 fp32 row-major; 1 bf16 row-major; 2 chan-major fp32 + residual;
//      3 silu(x+bias) bf16; 4 (x+bias) bf16; 5 split bf16 (outB0|outB1).
// ---------------------------------------------------------------------------
struct MSeg {
  const u16 *A0, *A1, *Wt;
  const float *bias, *res;
  float* outF; u16 *outB0, *outB1;
  int K, K1, Nout, ldA, ldo, split, nbx, nwg, epi;
};
struct MPack { MSeg s[4]; int starts[4]; int nseg; };

__global__ __launch_bounds__(256) void mfma_pack_k(MPack pk) {
  const int bid = blockIdx.x;
  int si = 0;
  #pragma unroll
  for (int k = 1; k < 4; ++k)
    if (k < pk.nseg && bid >= pk.starts[k]) si = k;
  const MSeg p = pk.s[si];
  const int wg = bid - pk.starts[si];

  __shared__ u16 lds[16384];            // As[2][4096] | Bs[2][4096]; reused as C-tile
  u16* As0 = lds;
  u16* Bs0 = lds + 8192;
  const int tid = threadIdx.x;
  const int lane = tid & 63;
  const int wid = tid >> 6;
  const int wm = wid >> 1, wn = wid & 1;
  const int newid = (wg & 7) * (p.nwg >> 3) + (wg >> 3);
  const int n0 = (newid % p.nbx) * 128;
  const int m0 = (newid / p.nbx) * 128;
  const int srow = tid & 127;
  const int skc = tid >> 7;
  const int kgrp = lane >> 4, l16 = lane & 15;

  f32x4 acc[4][4];
  #pragma unroll
  for (int i = 0; i < 4; ++i)
    #pragma unroll
    for (int j = 0; j < 4; ++j)
      acc[i][j] = (f32x4){0.f, 0.f, 0.f, 0.f};

  auto stage = [&](int bi, int k0) {
    const u16* Ab = p.A0;
    int kc = k0;
    if (p.A1 && k0 >= p.K1) { Ab = p.A1; kc = k0 - p.K1; }
    const u16* g0 = Ab + (size_t)(m0 + srow) * p.ldA + kc + skc * 8;
    u16* Ad = As0 + bi * 4096;
    __builtin_amdgcn_global_load_lds((const glb_u32*)g0,
        (lds_u32*)(Ad + wid * 512), 16, 0, 0);
    __builtin_amdgcn_global_load_lds((const glb_u32*)(g0 + 16),
        (lds_u32*)(Ad + 2048 + wid * 512), 16, 0, 0);
    const u16* h0 = p.Wt + (size_t)(n0 + srow) * p.K + k0 + skc * 8;
    u16* Bd = Bs0 + bi * 4096;
    __builtin_amdgcn_global_load_lds((const glb_u32*)h0,
        (lds_u32*)(Bd + wid * 512), 16, 0, 0);
    __builtin_amdgcn_global_load_lds((const glb_u32*)(h0 + 16),
        (lds_u32*)(Bd + 2048 + wid * 512), 16, 0, 0);
  };

  const int nt = p.K >> 5;
  stage(0, 0);
  __syncthreads();
  for (int t = 0; t < nt; ++t) {
    const int cur = t & 1;
    if (t + 1 < nt) stage(cur ^ 1, (t + 1) << 5);
    s16x8 af[4], bfr[4];
    #pragma unroll
    for (int mi = 0; mi < 4; ++mi)
      af[mi] = *(const s16x8*)(As0 + cur * 4096 + kgrp * 1024 + (wm * 64 + mi * 16 + l16) * 8);
    #pragma unroll
    for (int ni = 0; ni < 4; ++ni)
      bfr[ni] = *(const s16x8*)(Bs0 + cur * 4096 + kgrp * 1024 + (wn * 64 + ni * 16 + l16) * 8);
    #pragma unroll
    for (int mi = 0; mi < 4; ++mi)
      #pragma unroll
      for (int ni = 0; ni < 4; ++ni)
        acc[mi][ni] = __builtin_amdgcn_mfma_f32_16x16x32_bf16(af[mi], bfr[ni], acc[mi][ni], 0, 0, 0);
    if (t + 1 < nt) __syncthreads();
  }

  if (p.epi == 0) {
    #pragma unroll
    for (int mi = 0; mi < 4; ++mi) {
      #pragma unroll
      for (int j = 0; j < 4; ++j) {
        int token = m0 + wm * 64 + mi * 16 + (lane >> 4) * 4 + j;
        #pragma unroll
        for (int ni = 0; ni < 4; ++ni) {
          int n = n0 + wn * 64 + ni * 16 + l16;
          if (n < p.Nout) p.outF[(size_t)token * p.ldo + n] = acc[mi][ni][j];
        }
      }
    }
  } else if (p.epi == 2) {
    #pragma unroll
    for (int mi = 0; mi < 4; ++mi) {
      int token = m0 + wm * 64 + mi * 16 + (lane >> 4) * 4;
      int b = token >> 12, l = token & (L - 1);
      #pragma unroll
      for (int ni = 0; ni < 4; ++ni) {
        int n = n0 + wn * 64 + ni * 16 + l16;
        if (n < p.Nout) {
          size_t o = ((size_t)b * p.Nout + n) * L + l;
          float4 r = *(const float4*)(p.res + o);
          float4 v = make_float4(acc[mi][ni][0] + r.x, acc[mi][ni][1] + r.y,
                                 acc[mi][ni][2] + r.z, acc[mi][ni][3] + r.w);
          *(float4*)(p.outF + o) = v;
        }
      }
    }
  } else {
    // bf16 epis (1,3,4,5): stage C through XOR-swizzled LDS, coalesced stores
    __syncthreads();   // all waves done with As/Bs
    #pragma unroll
    for (int mi = 0; mi < 4; ++mi) {
      #pragma unroll
      for (int j = 0; j < 4; ++j) {
        int tok = wm * 64 + mi * 16 + (lane >> 4) * 4 + j;
        #pragma unroll
        for (int ni = 0; ni < 4; ++ni) {
          int nl = wn * 64 + ni * 16 + l16;
          int n = n0 + nl;
          float v = acc[mi][ni][j];
          if (n < p.Nout && (p.epi == 3 || p.epi == 4)) {
            v += p.bias[n];
            if (p.epi == 3) v = silu_f(v);
          }
          lds[tok * 128 + ((((nl >> 4) ^ (tok & 7))) << 4) + (nl & 15)] = f2bf(v);
        }
      }
    }
    __syncthreads();
    #pragma unroll
    for (int it = 0; it < 8; ++it) {
      int idx = it * 256 + tid;
      int row = idx >> 4, c16 = idx & 15;
      int nl0 = c16 * 8;
      if (n0 + nl0 < p.Nout) {
        int g = nl0 >> 4;
        int4 vv = *(const int4*)(lds + row * 128 + ((g ^ (row & 7)) << 4) + (nl0 & 15));
        int token = m0 + row;
        if (p.epi == 5) {
          int n = n0 + nl0;
          if (n < p.split) *(int4*)(p.outB0 + (size_t)token * p.split + n) = vv;
          else *(int4*)(p.outB1 + (size_t)token * p.split + (n - p.split)) = vv;
        } else {
          *(int4*)(p.outB0 + (size_t)token * p.ldo + n0 + nl0) = vv;
        }
      }
    }
  }
}

// ---------------------------------------------------------------------------
// Packed small fp32 GEMM (dt projections): softplus(x + eb[n]) epilogue
// ---------------------------------------------------------------------------
struct FSeg { const float* A0; const float* W; const float* eb; float* out; int K, N, lda, ldo, nbx; };
struct FPack { FSeg s[2]; int start1; };

__global__ __launch_bounds__(256) void gemm_f32_pack_k(FPack pk) {
  const int bid = blockIdx.x;
  const int si = bid >= pk.start1;
  const FSeg p = pk.s[si];
  const int local = si ? bid - pk.start1 : bid;
  const int n0 = (local % p.nbx) * 64;
  const int m0 = (local / p.nbx) * 64;

  __shared__ __align__(16) float As[16][64];
  __shared__ __align__(16) float Bs[16][64];
  const int tid = threadIdx.x;
  const int kidx = tid >> 4;
  const int li4 = (tid & 15) << 2;
  const int r0 = (tid & 15) << 2;
  const int c0 = (tid >> 4) << 2;
  float acc[4][4] = {};

  for (int k0 = 0; k0 < p.K; k0 += 16) {
    __syncthreads();
    {
      const int row = tid >> 2;
      const int kk4 = (tid & 3) << 2;
      const float* src = p.A0 + (size_t)(m0 + row) * p.lda;
      #pragma unroll
      for (int j = 0; j < 4; ++j) {
        int k = k0 + kk4 + j;
        As[kk4 + j][row] = (k < p.K) ? src[k] : 0.f;
      }
    }
    {
      int k = k0 + kidx;
      #pragma unroll
      for (int j = 0; j < 4; ++j) {
        int n = n0 + li4 + j;
        Bs[kidx][li4 + j] = (k < p.K && n < p.N) ? p.W[(size_t)k * p.N + n] : 0.f;
      }
    }
    __syncthreads();
    #pragma unroll
    for (int kk = 0; kk < 16; ++kk) {
      float4 a = *(const float4*)&As[kk][r0];
      float4 bq = *(const float4*)&Bs[kk][c0];
      float av[4] = {a.x, a.y, a.z, a.w};
      float bv[4] = {bq.x, bq.y, bq.z, bq.w};
      #pragma unroll
      for (int i = 0; i < 4; ++i)
        #pragma unroll
        for (int j = 0; j < 4; ++j)
          acc[i][j] = fmaf(av[i], bv[j], acc[i][j]);
    }
  }
  float eb[4] = {p.eb[n0 + c0], p.eb[n0 + c0 + 1], p.eb[n0 + c0 + 2], p.eb[n0 + c0 + 3]};
  #pragma unroll
  for (int i = 0; i < 4; ++i) {
    float4 v;
    v.x = softplus_f(acc[i][0] + eb[0]);
    v.y = softplus_f(acc[i][1] + eb[1]);
    v.z = softplus_f(acc[i][2] + eb[2]);
    v.w = softplus_f(acc[i][3] + eb[3]);
    *(float4*)&p.out[(size_t)(m0 + r0 + i) * p.ldo + n0 + c0] = v;
  }
}

// ---------------------------------------------------------------------------
// Packed chunked selective scan v5 (R13-best): block = (b, chunk, 192-ch slice).
// 256 threads cooperatively stage the chunk's B[/C] columns into LDS once;
// 192 scan threads read them as broadcast ds_read_b128. dlt precomputed fp32.
// Fast decay path: An[n]==(n+1)*An[0] (runtime-checked) => 1 exp + 15 muls.
// PF layout [c][slot 0..31][NCH]: slots 0..15 = P, 16..31 = F/Hin.
// ---------------------------------------------------------------------------
struct S3Seg {
  const u16* u; const float* dlt; const float* Alog; const float* xdbl;
  const float* Dp; const u16* zT; float* PF; u16* yT;
  int roff, Dch, CLen, NCH, nsl;
};
struct S3Pack { S3Seg s[2]; int start1; };

template<int PASS>
__global__ __launch_bounds__(256) void scan3_pack_k(S3Pack pk) {
  __shared__ float rows[64][32];
  const int bid = blockIdx.x;
  const int si = bid >= pk.start1;
  const S3Seg q = pk.s[si];
  const int local = si ? bid - pk.start1 : bid;
  const int nsl = q.nsl;
  const int NC = L / q.CLen;
  const int slice = local % nsl;
  const int c = (local / nsl) % NC;
  const int b = local / (nsl * NC);
  const int tid = threadIdx.x;
  const size_t tok0 = (size_t)b * L + (size_t)c * q.CLen;

  // cooperative stage: B cols (pass1) or B+C cols (pass3)
  const int W2 = (PASS == 1) ? 8 : 16;     // float2 count per row
  const int tot2 = q.CLen * W2;
  for (int i = tid; i < tot2; i += 256) {
    int r = i / W2, j = i - r * W2;
    float2 v = *(const float2*)(q.xdbl + (tok0 + r) * 64 + q.roff + 2 * j);
    *(float2*)&rows[r][2 * j] = v;
  }
  __syncthreads();

  if (tid < 192) {
    const int d = slice * 192 + tid;
    const int Dch = q.Dch;
    float An[16], h[16];
    #pragma unroll
    for (int n = 0; n < 16; ++n) {
      An[n] = -__expf(q.Alog[d * 16 + n]);
      h[n] = 0.f;
    }
    bool fast = true;
    #pragma unroll
    for (int n = 1; n < 16; ++n) {
      float ref = (float)(n + 1) * An[0];
      if (fabsf(An[n] - ref) > 1e-4f * fabsf(ref)) fast = false;
    }
    const int ch = b * Dch + d;
    if (PASS == 3) {
      #pragma unroll
      for (int n = 0; n < 16; ++n)
        h[n] = q.PF[((size_t)c * 32 + 16 + n) * q.NCH + ch];
    }
    const float Dd = q.Dp[d];
    const u16* up = q.u + tok0 * Dch + d;
    const float* dp = q.dlt + tok0 * Dch + d;
    const u16* zp = q.zT + tok0 * Dch + d;
    u16* yr = q.yT + tok0 * Dch + d;
    float S = 0.f;

    #define SCAN_BODY(FAST)                                                    \
    for (int t = 0; t < q.CLen; ++t) {                                         \
      const size_t od = (size_t)t * Dch;                                       \
      float dl = dp[od];                                                       \
      float uu = bf2f(up[od]);                                                 \
      float w = dl * uu;                                                       \
      f32x4 B4[4];                                                             \
      _Pragma("unroll")                                                        \
      for (int g = 0; g < 4; ++g) B4[g] = *(const f32x4*)&rows[t][4 * g];      \
      if (PASS == 1) S += dl;                                                  \
      float y = 0.f;                                                           \
      if (FAST) {                                                              \
        float a = __expf(dl * An[0]);                                          \
        float e = a;                                                           \
        h[0] = fmaf(e, h[0], w * B4[0][0]);                                    \
        _Pragma("unroll")                                                      \
        for (int n = 1; n < 16; ++n) {                                         \
          e *= a;                                                              \
          h[n] = fmaf(e, h[n], w * B4[n >> 2][n & 3]);                         \
        }                                                                      \
      } else {                                                                 \
        _Pragma("unroll")                                                      \
        for (int n = 0; n < 16; ++n)                                           \
          h[n] = fmaf(__expf(dl * An[n]), h[n], w * B4[n >> 2][n & 3]);        \
      }                                                                        \
      if (PASS == 3) {                                                         \
        f32x4 C4[4];                                                           \
        _Pragma("unroll")                                                      \
        for (int g = 0; g < 4; ++g) C4[g] = *(const f32x4*)&rows[t][16 + 4 * g]; \
        _Pragma("unroll")                                                      \
        for (int n = 0; n < 16; ++n)                                           \
          y = fmaf(h[n], C4[n >> 2][n & 3], y);                                \
        float zv = bf2f(zp[od]);                                               \
        yr[od] = f2bf((y + Dd * uu) * silu_f(zv));                             \
      }                                                                        \
    }

    if (fast) { SCAN_BODY(1) } else { SCAN_BODY(0) }
    #undef SCAN_BODY

    if (PASS == 1) {
      #pragma unroll
      for (int n = 0; n < 16; ++n) {
        q.PF[((size_t)c * 32 + n) * q.NCH + ch] = __expf(An[n] * S);
        q.PF[((size_t)c * 32 + 16 + n) * q.NCH + ch] = h[n];
      }
    }
  }
}

// Packed stitch: per (ch, state) sequential over chunks; rewrites F with Hin.
__global__ __launch_bounds__(256) void stitch_pack_k(
    float* PF0, int NC0, int NCH0, int tot0,
    float* PF1, int NC1, int NCH1, int tot1) {
  int idx = blockIdx.x * 256 + threadIdx.x;
  float* PF; int NC, NCH;
  if (idx < tot0) { PF = PF0; NC = NC0; NCH = NCH0; }
  else { idx -= tot0; if (idx >= tot1) return; PF = PF1; NC = NC1; NCH = NCH1; }
  int ch = idx % NCH, n = idx / NCH;
  float hin = 0.f;
  for (int c = 0; c < NC; ++c) {
    float* Ps = PF + ((size_t)c * 32 + n) * NCH + ch;
    float* Fs = PF + ((size_t)c * 32 + 16 + n) * NCH + ch;
    float Pv = *Ps, Fv = *Fs;
    *Fs = hin;
    hin = fmaf(Pv, hin, Fv);
  }
}

// ---------------------------------------------------------------------------
extern "C" void kernel_launch(void* const* d_in, const int* in_sizes, int n_in,
                              void* d_out, int out_size, void* d_ws, size_t ws_size,
                              hipStream_t stream) {
  const float* m_ll    = (const float*)d_in[0];
  const float* m_high  = (const float*)d_in[1];
  const float* zanc    = (const float*)d_in[2];
  const float* Kin     = (const float*)d_in[3];
  const float* Qin     = (const float*)d_in[4];
  const float* s_in_w  = (const float*)d_in[5];
  const float* s_conv_w= (const float*)d_in[6];
  const float* s_conv_b= (const float*)d_in[7];
  const float* s_x_w   = (const float*)d_in[8];
  const float* s_dt_w  = (const float*)d_in[9];
  const float* s_dt_b  = (const float*)d_in[10];
  const float* s_Alog  = (const float*)d_in[11];
  const float* s_D     = (const float*)d_in[12];
  const float* s_out_w = (const float*)d_in[13];
  const float* t_in_w  = (const float*)d_in[14];
  const float* t_conv_w= (const float*)d_in[15];
  const float* t_conv_b= (const float*)d_in[16];
  const float* t_kln_g = (const float*)d_in[17];
  const float* t_kln_b = (const float*)d_in[18];
  const float* t_k_w   = (const float*)d_in[19];
  const float* t_k_b   = (const float*)d_in[20];
  const float* t_qln_g = (const float*)d_in[21];
  const float* t_qln_b = (const float*)d_in[22];
  const float* t_q_w   = (const float*)d_in[23];
  const float* t_q_b   = (const float*)d_in[24];
  const float* t_dtbc_w= (const float*)d_in[25];
  const float* t_dt_w  = (const float*)d_in[26];
  const float* t_dt_b  = (const float*)d_in[27];
  const float* t_gate_w= (const float*)d_in[28];
  const float* t_gate_b= (const float*)d_in[29];
  const float* t_Alog  = (const float*)d_in[30];
  const float* t_D     = (const float*)d_in[31];
  const float* t_out_w = (const float*)d_in[32];

  float* out1 = (float*)d_out;               // (4, 96, 4096)
  float* out2 = out1 + (size_t)4 * 96 * L;   // (4, 288, 4096) = 4,718,592 f
  float* ws = (float*)d_ws;

  // Weights (bf16) — sizes in float units = (u16 count)/2
  u16* w_sin   = (u16*)(ws + 0);        // [384][96]   = 18,432 f
  u16* w_sx    = (u16*)(ws + 18432);    // [128][192]  = 12,288 f
  u16* w_sout  = (u16*)(ws + 30720);    // [128][192]  = 12,288 f
  u16* w_tin   = (u16*)(ws + 43008);    // [640][288]  = 92,160 f
  u16* w_tk    = (u16*)(ws + 135168);   // [640][288]
  u16* w_tq    = (u16*)(ws + 227328);   // [640][288]
  u16* w_tdtbc = (u16*)(ws + 319488);   // [128][1152] = 73,728 f
  u16* w_tgate = (u16*)(ws + 393216);   // [640][1152] = 368,640 f
  u16* w_tout  = (u16*)(ws + 761856);   // [384][576]  = 110,592 f -> ends 872,448

  // Activations (u16 [16384][C] = 8192*C floats)
  float* B_ahi  = ws + 872448;    // u16[16384][288] = 2,359,296 f -> 3,231,744
  float* B_aK   = ws + 3231744;   // -> 5,591,040
  float* B_aQ   = ws + 5591040;   // -> 7,950,336
  float* B_all  = ws + 7950336;   // u16[16384][96] = 786,432 f -> 8,736,768
  float* B_xin  = ws + 8736768;   // u16[16384][192] = 1,572,864 f -> 10,309,632
  float* B_zTs  = ws + 10309632;  // -> 11,882,496
  float* B_xc   = ws + 11882496;  // -> 13,455,360
  float* B_xin3 = ws + 13455360;  // u16[16384][576] = 4,718,592 f -> 18,173,952
  float* B_xc3  = ws + 18173952;  // -> 22,892,544
  float* B_kp   = ws + 22892544;  // -> 27,611,136
  float* B_qp   = ws + 27611136;  // -> 32,329,728
  float* B_zg3  = ws + 32329728;  // -> 37,048,320
  float* B_xdbl = ws + 37048320;  // fp32 [16384][64] -> 38,096,896
  float* B_xdbl3= ws + 38096896;  // -> 39,145,472
  float* B_PFs  = ws + 39145472;  // fp32 128*32*768 -> 42,291,200
  // Overlays (liveness-verified):
  float* B_dlt  = B_ahi;          // fp32 16384*192 over a_hi+aK (dead after P1)
  float* B_dlt3 = B_kp;           // fp32 16384*576 over kp+qp exactly (dead after P2)
  u16* y_bf = (u16*)B_xin;        // over x_in (dead after conv)
  u16* y3   = (u16*)B_xin3;       // over xin3 (dead after conv)
  float* PFt = out2;              // 64*32*2304 == |out2| (dead until P3)

  dim3 blk(256);

  // 1) weight conversion
  {
    WAll wa;
    wa.s[0] = {s_in_w,   w_sin,    96, 384, 384};
    wa.s[1] = {s_x_w,    w_sx,    192,  38, 128};
    wa.s[2] = {s_out_w,  w_sout,  192,  96, 128};
    wa.s[3] = {t_in_w,   w_tin,   288, 576, 640};
    wa.s[4] = {t_k_w,    w_tk,    288, 576, 640};
    wa.s[5] = {t_q_w,    w_tq,    288, 576, 640};
    wa.s[6] = {t_dtbc_w, w_tdtbc, 1152, 50, 128};
    wa.s[7] = {t_gate_w, w_tgate, 1152, 576, 640};
    wconv_k<<<dim3(20, 36, 8), blk, 0, stream>>>(wa);
    WAll wb;
    wb.s[0] = {t_out_w,  w_tout,  576, 288, 384};
    wconv_k<<<dim3(12, 18, 1), blk, 0, stream>>>(wb);
  }

  // 2) all four transpose-preps (4 x 512 blocks)
  {
    TPack tp{};
    tp.s[0] = {m_ll,   nullptr, nullptr, zanc,    (u16*)B_all, 96,  0};
    tp.s[1] = {m_high, nullptr, nullptr, nullptr, (u16*)B_ahi, 288, 0};
    tp.s[2] = {Kin,    t_kln_g, t_kln_b, nullptr, (u16*)B_aK,  288, 1};
    tp.s[3] = {Qin,    t_qln_g, t_qln_b, nullptr, (u16*)B_aQ,  288, 1};
    trans_pack_k<<<dim3(2048), blk, 0, stream>>>(tp);
  }

  // 3) P1: s_in + t_in + t_k + t_q (2304 blocks, 128^2 tiles)
  {
    MPack pk{}; pk.nseg = 4;
    pk.starts[0] = 0; pk.starts[1] = 384; pk.starts[2] = 1024; pk.starts[3] = 1664;
    MSeg a{}; a.A0 = (u16*)B_all; a.Wt = w_sin; a.K = 96; a.K1 = 1 << 28; a.Nout = 384;
    a.ldA = 96; a.split = 192; a.outB0 = (u16*)B_xin; a.outB1 = (u16*)B_zTs;
    a.nbx = 3; a.nwg = 384; a.epi = 5; pk.s[0] = a;
    MSeg b{}; b.A0 = (u16*)B_ahi; b.Wt = w_tin; b.K = 288; b.K1 = 1 << 28; b.Nout = 576;
    b.ldA = 288; b.ldo = 576; b.outB0 = (u16*)B_xin3; b.nbx = 5; b.nwg = 640; b.epi = 1; pk.s[1] = b;
    MSeg c{}; c.A0 = (u16*)B_aK; c.Wt = w_tk; c.K = 288; c.K1 = 1 << 28; c.Nout = 576;
    c.ldA = 288; c.ldo = 576; c.bias = t_k_b; c.outB0 = (u16*)B_kp; c.nbx = 5; c.nwg = 640; c.epi = 3; pk.s[2] = c;
    MSeg d{}; d.A0 = (u16*)B_aQ; d.Wt = w_tq; d.K = 288; d.K1 = 1 << 28; d.Nout = 576;
    d.ldA = 288; d.ldo = 576; d.bias = t_q_b; d.outB0 = (u16*)B_qp; d.nbx = 5; d.nwg = 640; d.epi = 3; pk.s[3] = d;
    mfma_pack_k<<<dim3(2304), blk, 0, stream>>>(pk);
  }

  // 4) both convs (1536 + 4608 blocks)
  {
    CPack cp{}; cp.start1 = 1536;
    cp.s[0] = {(u16*)B_xin,  s_conv_w, s_conv_b, (u16*)B_xc,  192, 3};
    cp.s[1] = {(u16*)B_xin3, t_conv_w, t_conv_b, (u16*)B_xc3, 576, 9};
    conv_pack_k<<<dim3(6144), blk, 0, stream>>>(cp);
  }

  // 5) P2: s_x + dtbc + gate (128 + 128 + 640 = 896 blocks)
  {
    MPack pk{}; pk.nseg = 3;
    pk.starts[0] = 0; pk.starts[1] = 128; pk.starts[2] = 256; pk.starts[3] = 896;
    MSeg a{}; a.A0 = (u16*)B_xc; a.Wt = w_sx; a.K = 192; a.K1 = 1 << 28; a.Nout = 64;
    a.ldA = 192; a.ldo = 64; a.outF = B_xdbl; a.nbx = 1; a.nwg = 128; a.epi = 0; pk.s[0] = a;
    MSeg b{}; b.A0 = (u16*)B_xc3; b.A1 = (u16*)B_kp; b.Wt = w_tdtbc; b.K = 1152; b.K1 = 576;
    b.Nout = 64; b.ldA = 576; b.ldo = 64; b.outF = B_xdbl3; b.nbx = 1; b.nwg = 128; b.epi = 0; pk.s[1] = b;
    MSeg c{}; c.A0 = (u16*)B_xc3; c.A1 = (u16*)B_qp; c.Wt = w_tgate; c.K = 1152; c.K1 = 576;
    c.Nout = 576; c.ldA = 576; c.ldo = 576; c.bias = t_gate_b; c.outB0 = (u16*)B_zg3;
    c.nbx = 5; c.nwg = 640; c.epi = 4; pk.s[2] = c;
    mfma_pack_k<<<dim3(896), blk, 0, stream>>>(pk);
  }

  // 6) both dt-projection fp32 GEMMs (768 + 2304 blocks)
  {
    FPack fp{}; fp.start1 = 768;
    fp.s[0] = {B_xdbl,  s_dt_w, s_dt_b, B_dlt,  6,  192, 64, 192, 3};
    fp.s[1] = {B_xdbl3, t_dt_w, t_dt_b, B_dlt3, 18, 576, 64, 576, 9};
    gemm_f32_pack_k<<<dim3(3072), blk, 0, stream>>>(fp);
  }

  // 7-9) scans (block = (b, chunk, 192-ch slice), LDS-staged B/C) + stitch
  // seg0: 4 b x 128 chunks x 1 slice = 512 blocks; seg1: 4 x 64 x 3 = 768.
  S3Pack sp{}; sp.start1 = 512;
  sp.s[0] = {(u16*)B_xc,  B_dlt,  s_Alog, B_xdbl,  s_D, (u16*)B_zTs, B_PFs, y_bf, 6,  192, 32, 768,  1};
  sp.s[1] = {(u16*)B_xc3, B_dlt3, t_Alog, B_xdbl3, t_D, (u16*)B_zg3, PFt,   y3,   18, 576, 64, 2304, 3};
  scan3_pack_k<1><<<dim3(1280), blk, 0, stream>>>(sp);
  stitch_pack_k<<<dim3(192), blk, 0, stream>>>(B_PFs, 128, 768, 12288, PFt, 64, 2304, 36864);
  scan3_pack_k<3><<<dim3(1280), blk, 0, stream>>>(sp);

  // 10) P3: s_out + t_out (128 + 384 = 512 blocks)
  {
    MPack pk{}; pk.nseg = 2;
    pk.starts[0] = 0; pk.starts[1] = 128; pk.starts[2] = 512; pk.starts[3] = 512;
    MSeg a{}; a.A0 = y_bf; a.Wt = w_sout; a.K = 192; a.K1 = 1 << 28; a.Nout = 96;
    a.ldA = 192; a.res = m_ll; a.outF = out1; a.nbx = 1; a.nwg = 128; a.epi = 2; pk.s[0] = a;
    MSeg b{}; b.A0 = y3; b.Wt = w_tout; b.K = 576; b.K1 = 1 << 28; b.Nout = 288;
    b.ldA = 576; b.res = m_high; b.outF = out2; b.nbx = 3; b.nwg = 384; b.epi = 2; pk.s[1] = b;
    mfma_pack_k<<<dim3(512), blk, 0, stream>>>(pk);
  }
}

// Round 17
// 388.165 us; speedup vs baseline: 1.1487x; 1.0237x over previous
//
#include <hip/hip_runtime.h>
#include <math.h>

// DualStreamBlock: B=4, DIM=96, DIM3=288, H=W=64, L=4096, DSTATE=16
#define L 4096

typedef unsigned short u16;
typedef unsigned int u32;
typedef float f32x4 __attribute__((ext_vector_type(4)));
typedef short s16x8 __attribute__((ext_vector_type(8)));
typedef __attribute__((address_space(3))) unsigned int lds_u32;
typedef __attribute__((address_space(1))) unsigned int glb_u32;

__device__ __forceinline__ float softplus_f(float x) {
  return fmaxf(x, 0.f) + log1pf(__expf(-fabsf(x)));
}
__device__ __forceinline__ float silu_f(float x) {
  return x / (1.f + __expf(-x));
}
__device__ __forceinline__ float bf2f(u16 v) {
  return __uint_as_float(((unsigned)v) << 16);
}
__device__ __forceinline__ u16 f2bf(float f) {
  unsigned u = __float_as_uint(f);
  u += 0x7FFFu + ((u >> 16) & 1u);
  return (u16)(u >> 16);
}

// ---------------------------------------------------------------------------
// Weight convert: fp32 W[K][N] -> bf16 Wt[Npad][K] (transposed, zero-padded)
// ---------------------------------------------------------------------------
struct WSeg { const float* src; u16* dst; int K, N, Npad; };
struct WAll { WSeg s[8]; };

__global__ __launch_bounds__(256) void wconv_k(WAll wa) {
  const WSeg w = wa.s[blockIdx.z];
  const int nb = blockIdx.x * 32, kb = blockIdx.y * 32;
  if (nb >= w.Npad || kb >= w.K) return;
  __shared__ float t[32][33];
  const int tx = threadIdx.x & 31, ty = threadIdx.x >> 5;
  for (int r = ty; r < 32; r += 8) {
    int k = kb + r, n = nb + tx;
    t[r][tx] = (n < w.N) ? w.src[(size_t)k * w.N + n] : 0.f;
  }
  __syncthreads();
  for (int r = ty; r < 32; r += 8) {
    int n = nb + r;
    w.dst[(size_t)n * w.K + kb + tx] = f2bf(t[tx][r]);
  }
}

// ---------------------------------------------------------------------------
// Packed transpose prep: 4 segments x 512 blocks. chan-major fp32 -> token-major
// bf16. Per-segment: optional LN over C, optional +bias2[b*C+c].
// ---------------------------------------------------------------------------
struct TSeg { const float *x, *gam, *bet, *bias2; u16* out; int C, doLN; };
struct TPack { TSeg s[4]; };

__global__ __launch_bounds__(256) void trans_pack_k(TPack pk) {
  const TSeg t = pk.s[blockIdx.x >> 9];
  const int local = blockIdx.x & 511;
  const int C = t.C;
  __shared__ float tile[288][33];
  __shared__ float psum[8][32], psq[8][32];
  __shared__ float mm[32], rr[32];
  const int tid = threadIdx.x;
  const int l0 = (local & 127) * 32;
  const int b = local >> 7;
  const int lane32 = tid & 31, row8 = tid >> 5;
  const float* xb = t.x + (size_t)b * C * L + l0;

  for (int c = row8; c < C; c += 8)
    tile[c][lane32] = xb[(size_t)c * L + lane32];
  __syncthreads();

  if (t.doLN) {
    float s = 0.f, sq = 0.f;
    for (int c = row8; c < C; c += 8) {
      float v = tile[c][lane32];
      s += v; sq = fmaf(v, v, sq);
    }
    psum[row8][lane32] = s; psq[row8][lane32] = sq;
    __syncthreads();
    if (row8 == 0) {
      float ts = 0.f, tq = 0.f;
      #pragma unroll
      for (int g = 0; g < 8; ++g) { ts += psum[g][lane32]; tq += psq[g][lane32]; }
      float m = ts / C;
      float var = tq / C - m * m;
      mm[lane32] = m;
      rr[lane32] = rsqrtf(var + 1e-5f);
    }
    __syncthreads();
  }

  u16* ob = t.out + ((size_t)b * L + l0) * C;
  const int total = 32 * C;
  for (int o = tid * 8; o < total; o += 2048) {
    int tt = o / C, c = o % C;
    float m = 0.f, rs = 0.f;
    if (t.doLN) { m = mm[tt]; rs = rr[tt]; }
    union { u16 u[8]; int4 v; } pkv;
    #pragma unroll
    for (int j = 0; j < 8; ++j) {
      float v = tile[c + j][tt];
      if (t.doLN) v = (v - m) * rs * t.gam[c + j] + t.bet[c + j];
      else if (t.bias2) v += t.bias2[b * C + c + j];
      pkv.u[j] = f2bf(v);
    }
    *(int4*)(ob + o) = pkv.v;
  }
}

// ---------------------------------------------------------------------------
// Packed causal depthwise conv k=4 + bias + silu, token-major bf16 (2 segments)
// ---------------------------------------------------------------------------
struct CSeg { const u16* x; const float* w; const float* b; u16* y; int C, nbx; };
struct CPack { CSeg s[2]; int start1; };

__global__ __launch_bounds__(256) void conv_pack_k(CPack pk) {
  const int bid = blockIdx.x;
  const int si = bid >= pk.start1;
  const CSeg q = pk.s[si];
  const int local = si ? bid - pk.start1 : bid;
  const int C = q.C;
  const int c = (local % q.nbx) * 64 + (threadIdx.x & 63);
  const int chunk = (local / q.nbx) * 4 + (threadIdx.x >> 6);
  const int T0 = chunk * 8;
  const float w0 = q.w[c * 4], w1 = q.w[c * 4 + 1], w2 = q.w[c * 4 + 2], w3 = q.w[c * 4 + 3];
  const float bs = q.b[c];
  const bool first = (T0 & (L - 1)) == 0;
  float v[11];
  #pragma unroll
  for (int i = 0; i < 11; ++i) {
    if (i < 3 && first) v[i] = 0.f;
    else v[i] = bf2f(q.x[(size_t)(T0 - 3 + i) * C + c]);
  }
  #pragma unroll
  for (int j = 0; j < 8; ++j) {
    float s = bs + w0 * v[j] + w1 * v[j + 1] + w2 * v[j + 2] + w3 * v[j + 3];
    q.y[(size_t)(T0 + j) * C + c] = f2bf(silu_f(s));
  }
}

// ---------------------------------------------------------------------------
// Packed MFMA bf16 GEMM (up to 4 segments). Tile 128x128, 4 waves (2x2), BK=32,
// 2-stage double-buffer (32KB LDS), global_load_lds, per-segment XCD swizzle.
// bf16 epilogues (1,3,4,5) route through a 32KB XOR-swizzled LDS C-tile and
// store coalesced int4 rows.
// epi: 0 fp32 row-major; 1 bf16 row-major; 2 chan-major fp32 + residual;
//      3 silu(x+bias) bf16; 4 (x+bias) bf16; 5 split bf16 (outB0|outB1).
// ---------------------------------------------------------------------------
struct MSeg {
  const u16 *A0, *A1, *Wt;
  const float *bias, *res;
  float* outF; u16 *outB0, *outB1;
  int K, K1, Nout, ldA, ldo, split, nbx, nwg, epi;
};
struct MPack { MSeg s[4]; int starts[4]; int nseg; };

__global__ __launch_bounds__(256) void mfma_pack_k(MPack pk) {
  const int bid = blockIdx.x;
  int si = 0;
  #pragma unroll
  for (int k = 1; k < 4; ++k)
    if (k < pk.nseg && bid >= pk.starts[k]) si = k;
  const MSeg p = pk.s[si];
  const int wg = bid - pk.starts[si];

  __shared__ u16 lds[16384];            // As[2][4096] | Bs[2][4096]; reused as C-tile
  u16* As0 = lds;
  u16* Bs0 = lds + 8192;
  const int tid = threadIdx.x;
  const int lane = tid & 63;
  const int wid = tid >> 6;
  const int wm = wid >> 1, wn = wid & 1;
  const int newid = (wg & 7) * (p.nwg >> 3) + (wg >> 3);
  const int n0 = (newid % p.nbx) * 128;
  const int m0 = (newid / p.nbx) * 128;
  const int srow = tid & 127;
  const int skc = tid >> 7;
  const int kgrp = lane >> 4, l16 = lane & 15;

  f32x4 acc[4][4];
  #pragma unroll
  for (int i = 0; i < 4; ++i)
    #pragma unroll
    for (int j = 0; j < 4; ++j)
      acc[i][j] = (f32x4){0.f, 0.f, 0.f, 0.f};

  auto stage = [&](int bi, int k0) {
    const u16* Ab = p.A0;
    int kc = k0;
    if (p.A1 && k0 >= p.K1) { Ab = p.A1; kc = k0 - p.K1; }
    const u16* g0 = Ab + (size_t)(m0 + srow) * p.ldA + kc + skc * 8;
    u16* Ad = As0 + bi * 4096;
    __builtin_amdgcn_global_load_lds((const glb_u32*)g0,
        (lds_u32*)(Ad + wid * 512), 16, 0, 0);
    __builtin_amdgcn_global_load_lds((const glb_u32*)(g0 + 16),
        (lds_u32*)(Ad + 2048 + wid * 512), 16, 0, 0);
    const u16* h0 = p.Wt + (size_t)(n0 + srow) * p.K + k0 + skc * 8;
    u16* Bd = Bs0 + bi * 4096;
    __builtin_amdgcn_global_load_lds((const glb_u32*)h0,
        (lds_u32*)(Bd + wid * 512), 16, 0, 0);
    __builtin_amdgcn_global_load_lds((const glb_u32*)(h0 + 16),
        (lds_u32*)(Bd + 2048 + wid * 512), 16, 0, 0);
  };

  const int nt = p.K >> 5;
  stage(0, 0);
  __syncthreads();
  for (int t = 0; t < nt; ++t) {
    const int cur = t & 1;
    if (t + 1 < nt) stage(cur ^ 1, (t + 1) << 5);
    s16x8 af[4], bfr[4];
    #pragma unroll
    for (int mi = 0; mi < 4; ++mi)
      af[mi] = *(const s16x8*)(As0 + cur * 4096 + kgrp * 1024 + (wm * 64 + mi * 16 + l16) * 8);
    #pragma unroll
    for (int ni = 0; ni < 4; ++ni)
      bfr[ni] = *(const s16x8*)(Bs0 + cur * 4096 + kgrp * 1024 + (wn * 64 + ni * 16 + l16) * 8);
    #pragma unroll
    for (int mi = 0; mi < 4; ++mi)
      #pragma unroll
      for (int ni = 0; ni < 4; ++ni)
        acc[mi][ni] = __builtin_amdgcn_mfma_f32_16x16x32_bf16(af[mi], bfr[ni], acc[mi][ni], 0, 0, 0);
    if (t + 1 < nt) __syncthreads();
  }

  if (p.epi == 0) {
    #pragma unroll
    for (int mi = 0; mi < 4; ++mi) {
      #pragma unroll
      for (int j = 0; j < 4; ++j) {
        int token = m0 + wm * 64 + mi * 16 + (lane >> 4) * 4 + j;
        #pragma unroll
        for (int ni = 0; ni < 4; ++ni) {
          int n = n0 + wn * 64 + ni * 16 + l16;
          if (n < p.Nout) p.outF[(size_t)token * p.ldo + n] = acc[mi][ni][j];
        }
      }
    }
  } else if (p.epi == 2) {
    #pragma unroll
    for (int mi = 0; mi < 4; ++mi) {
      int token = m0 + wm * 64 + mi * 16 + (lane >> 4) * 4;
      int b = token >> 12, l = token & (L - 1);
      #pragma unroll
      for (int ni = 0; ni < 4; ++ni) {
        int n = n0 + wn * 64 + ni * 16 + l16;
        if (n < p.Nout) {
          size_t o = ((size_t)b * p.Nout + n) * L + l;
          float4 r = *(const float4*)(p.res + o);
          float4 v = make_float4(acc[mi][ni][0] + r.x, acc[mi][ni][1] + r.y,
                                 acc[mi][ni][2] + r.z, acc[mi][ni][3] + r.w);
          *(float4*)(p.outF + o) = v;
        }
      }
    }
  } else {
    // bf16 epis (1,3,4,5): stage C through XOR-swizzled LDS, coalesced stores
    __syncthreads();   // all waves done with As/Bs
    #pragma unroll
    for (int mi = 0; mi < 4; ++mi) {
      #pragma unroll
      for (int j = 0; j < 4; ++j) {
        int tok = wm * 64 + mi * 16 + (lane >> 4) * 4 + j;
        #pragma unroll
        for (int ni = 0; ni < 4; ++ni) {
          int nl = wn * 64 + ni * 16 + l16;
          int n = n0 + nl;
          float v = acc[mi][ni][j];
          if (n < p.Nout && (p.epi == 3 || p.epi == 4)) {
            v += p.bias[n];
            if (p.epi == 3) v = silu_f(v);
          }
          lds[tok * 128 + ((((nl >> 4) ^ (tok & 7))) << 4) + (nl & 15)] = f2bf(v);
        }
      }
    }
    __syncthreads();
    #pragma unroll
    for (int it = 0; it < 8; ++it) {
      int idx = it * 256 + tid;
      int row = idx >> 4, c16 = idx & 15;
      int nl0 = c16 * 8;
      if (n0 + nl0 < p.Nout) {
        int g = nl0 >> 4;
        int4 vv = *(const int4*)(lds + row * 128 + ((g ^ (row & 7)) << 4) + (nl0 & 15));
        int token = m0 + row;
        if (p.epi == 5) {
          int n = n0 + nl0;
          if (n < p.split) *(int4*)(p.outB0 + (size_t)token * p.split + n) = vv;
          else *(int4*)(p.outB1 + (size_t)token * p.split + (n - p.split)) = vv;
        } else {
          *(int4*)(p.outB0 + (size_t)token * p.ldo + n0 + nl0) = vv;
        }
      }
    }
  }
}

// ---------------------------------------------------------------------------
// Packed small fp32 GEMM (dt projections): softplus(x + eb[n]) epilogue
// ---------------------------------------------------------------------------
struct FSeg { const float* A0; const float* W; const float* eb; float* out; int K, N, lda, ldo, nbx; };
struct FPack { FSeg s[2]; int start1; };

__global__ __launch_bounds__(256) void gemm_f32_pack_k(FPack pk) {
  const int bid = blockIdx.x;
  const int si = bid >= pk.start1;
  const FSeg p = pk.s[si];
  const int local = si ? bid - pk.start1 : bid;
  const int n0 = (local % p.nbx) * 64;
  const int m0 = (local / p.nbx) * 64;

  __shared__ __align__(16) float As[16][64];
  __shared__ __align__(16) float Bs[16][64];
  const int tid = threadIdx.x;
  const int kidx = tid >> 4;
  const int li4 = (tid & 15) << 2;
  const int r0 = (tid & 15) << 2;
  const int c0 = (tid >> 4) << 2;
  float acc[4][4] = {};

  for (int k0 = 0; k0 < p.K; k0 += 16) {
    __syncthreads();
    {
      const int row = tid >> 2;
      const int kk4 = (tid & 3) << 2;
      const float* src = p.A0 + (size_t)(m0 + row) * p.lda;
      #pragma unroll
      for (int j = 0; j < 4; ++j) {
        int k = k0 + kk4 + j;
        As[kk4 + j][row] = (k < p.K) ? src[k] : 0.f;
      }
    }
    {
      int k = k0 + kidx;
      #pragma unroll
      for (int j = 0; j < 4; ++j) {
        int n = n0 + li4 + j;
        Bs[kidx][li4 + j] = (k < p.K && n < p.N) ? p.W[(size_t)k * p.N + n] : 0.f;
      }
    }
    __syncthreads();
    #pragma unroll
    for (int kk = 0; kk < 16; ++kk) {
      float4 a = *(const float4*)&As[kk][r0];
      float4 bq = *(const float4*)&Bs[kk][c0];
      float av[4] = {a.x, a.y, a.z, a.w};
      float bv[4] = {bq.x, bq.y, bq.z, bq.w};
      #pragma unroll
      for (int i = 0; i < 4; ++i)
        #pragma unroll
        for (int j = 0; j < 4; ++j)
          acc[i][j] = fmaf(av[i], bv[j], acc[i][j]);
    }
  }
  float eb[4] = {p.eb[n0 + c0], p.eb[n0 + c0 + 1], p.eb[n0 + c0 + 2], p.eb[n0 + c0 + 3]};
  #pragma unroll
  for (int i = 0; i < 4; ++i) {
    float4 v;
    v.x = softplus_f(acc[i][0] + eb[0]);
    v.y = softplus_f(acc[i][1] + eb[1]);
    v.z = softplus_f(acc[i][2] + eb[2]);
    v.w = softplus_f(acc[i][3] + eb[3]);
    *(float4*)&p.out[(size_t)(m0 + r0 + i) * p.ldo + n0 + c0] = v;
  }
}

// ---------------------------------------------------------------------------
// Packed chunked selective scan v8: block = (b, chunk, 192-ch slice).
// Same as R13-best v5, plus SPLIT PF (chunks < cSplit in PF, rest in PF2)
// so the STS segment can run CLen=32 (NC=128) without growing the workspace:
// PFt chunks 0..63 live in out2, chunks 64..127 in the dead aK/aQ/a_ll region.
// Grid doubles for STS: 4 x 128 x 3 = 1536 blocks (total 2048 = 8 blocks/CU).
// ---------------------------------------------------------------------------
struct S3Seg {
  const u16* u; const float* dlt; const float* Alog; const float* xdbl;
  const float* Dp; const u16* zT; float* PF; float* PF2; u16* yT;
  int roff, Dch, CLen, NCH, nsl, cSplit;
};
struct S3Pack { S3Seg s[2]; int start1; };

template<int PASS>
__global__ __launch_bounds__(256) void scan3_pack_k(S3Pack pk) {
  __shared__ float rows[64][32];
  const int bid = blockIdx.x;
  const int si = bid >= pk.start1;
  const S3Seg q = pk.s[si];
  const int local = si ? bid - pk.start1 : bid;
  const int nsl = q.nsl;
  const int NC = L / q.CLen;
  const int slice = local % nsl;
  const int c = (local / nsl) % NC;
  const int b = local / (nsl * NC);
  const int tid = threadIdx.x;
  const size_t tok0 = (size_t)b * L + (size_t)c * q.CLen;

  // split-PF base select (block-uniform)
  float* PFb;
  int cc;
  if (c < q.cSplit) { PFb = q.PF; cc = c; }
  else { PFb = q.PF2; cc = c - q.cSplit; }

  // cooperative stage: B cols (pass1) or B+C cols (pass3)
  const int W2 = (PASS == 1) ? 8 : 16;     // float2 count per row
  const int tot2 = q.CLen * W2;
  for (int i = tid; i < tot2; i += 256) {
    int r = i / W2, j = i - r * W2;
    float2 v = *(const float2*)(q.xdbl + (tok0 + r) * 64 + q.roff + 2 * j);
    *(float2*)&rows[r][2 * j] = v;
  }
  __syncthreads();

  if (tid < 192) {
    const int d = slice * 192 + tid;
    const int Dch = q.Dch;
    float An[16], h[16];
    #pragma unroll
    for (int n = 0; n < 16; ++n) {
      An[n] = -__expf(q.Alog[d * 16 + n]);
      h[n] = 0.f;
    }
    bool fast = true;
    #pragma unroll
    for (int n = 1; n < 16; ++n) {
      float ref = (float)(n + 1) * An[0];
      if (fabsf(An[n] - ref) > 1e-4f * fabsf(ref)) fast = false;
    }
    const int ch = b * Dch + d;
    if (PASS == 3) {
      #pragma unroll
      for (int n = 0; n < 16; ++n)
        h[n] = PFb[((size_t)cc * 32 + 16 + n) * q.NCH + ch];
    }
    const float Dd = q.Dp[d];
    const u16* up = q.u + tok0 * Dch + d;
    const float* dp = q.dlt + tok0 * Dch + d;
    const u16* zp = q.zT + tok0 * Dch + d;
    u16* yr = q.yT + tok0 * Dch + d;
    float S = 0.f;

    #define SCAN_BODY(FAST)                                                    \
    for (int t = 0; t < q.CLen; ++t) {                                         \
      const size_t od = (size_t)t * Dch;                                       \
      float dl = dp[od];                                                       \
      float uu = bf2f(up[od]);                                                 \
      float w = dl * uu;                                                       \
      f32x4 B4[4];                                                             \
      _Pragma("unroll")                                                        \
      for (int g = 0; g < 4; ++g) B4[g] = *(const f32x4*)&rows[t][4 * g];      \
      if (PASS == 1) S += dl;                                                  \
      float y = 0.f;                                                           \
      if (FAST) {                                                              \
        float a = __expf(dl * An[0]);                                          \
        float e = a;                                                           \
        h[0] = fmaf(e, h[0], w * B4[0][0]);                                    \
        _Pragma("unroll")                                                      \
        for (int n = 1; n < 16; ++n) {                                         \
          e *= a;                                                              \
          h[n] = fmaf(e, h[n], w * B4[n >> 2][n & 3]);                         \
        }                                                                      \
      } else {                                                                 \
        _Pragma("unroll")                                                      \
        for (int n = 0; n < 16; ++n)                                           \
          h[n] = fmaf(__expf(dl * An[n]), h[n], w * B4[n >> 2][n & 3]);        \
      }                                                                        \
      if (PASS == 3) {                                                         \
        f32x4 C4[4];                                                           \
        _Pragma("unroll")                                                      \
        for (int g = 0; g < 4; ++g) C4[g] = *(const f32x4*)&rows[t][16 + 4 * g]; \
        _Pragma("unroll")                                                      \
        for (int n = 0; n < 16; ++n)                                           \
          y = fmaf(h[n], C4[n >> 2][n & 3], y);                                \
        float zv = bf2f(zp[od]);                                               \
        yr[od] = f2bf((y + Dd * uu) * silu_f(zv));                             \
      }                                                                        \
    }

    if (fast) { SCAN_BODY(1) } else { SCAN_BODY(0) }
    #undef SCAN_BODY

    if (PASS == 1) {
      #pragma unroll
      for (int n = 0; n < 16; ++n) {
        PFb[((size_t)cc * 32 + n) * q.NCH + ch] = __expf(An[n] * S);
        PFb[((size_t)cc * 32 + 16 + n) * q.NCH + ch] = h[n];
      }
    }
  }
}

// Packed stitch with split-PF: per (ch, state) sequential over chunks;
// chunk c < split lives in PFa (index c), else PFb (index c-split).
__global__ __launch_bounds__(256) void stitch_pack_k(
    float* PA0, float* PB0, int sp0, int NC0, int NCH0, int tot0,
    float* PA1, float* PB1, int sp1, int NC1, int NCH1, int tot1) {
  int idx = blockIdx.x * 256 + threadIdx.x;
  float *PA, *PB; int sp, NC, NCH;
  if (idx < tot0) { PA = PA0; PB = PB0; sp = sp0; NC = NC0; NCH = NCH0; }
  else { idx -= tot0; if (idx >= tot1) return; PA = PA1; PB = PB1; sp = sp1; NC = NC1; NCH = NCH1; }
  int ch = idx % NCH, n = idx / NCH;
  float hin = 0.f;
  for (int c = 0; c < NC; ++c) {
    float* base = (c < sp) ? PA : PB;
    int cc = (c < sp) ? c : c - sp;
    float* Ps = base + ((size_t)cc * 32 + n) * NCH + ch;
    float* Fs = base + ((size_t)cc * 32 + 16 + n) * NCH + ch;
    float Pv = *Ps, Fv = *Fs;
    *Fs = hin;
    hin = fmaf(Pv, hin, Fv);
  }
}

// ---------------------------------------------------------------------------
extern "C" void kernel_launch(void* const* d_in, const int* in_sizes, int n_in,
                              void* d_out, int out_size, void* d_ws, size_t ws_size,
                              hipStream_t stream) {
  const float* m_ll    = (const float*)d_in[0];
  const float* m_high  = (const float*)d_in[1];
  const float* zanc    = (const float*)d_in[2];
  const float* Kin     = (const float*)d_in[3];
  const float* Qin     = (const float*)d_in[4];
  const float* s_in_w  = (const float*)d_in[5];
  const float* s_conv_w= (const float*)d_in[6];
  const float* s_conv_b= (const float*)d_in[7];
  const float* s_x_w   = (const float*)d_in[8];
  const float* s_dt_w  = (const float*)d_in[9];
  const float* s_dt_b  = (const float*)d_in[10];
  const float* s_Alog  = (const float*)d_in[11];
  const float* s_D     = (const float*)d_in[12];
  const float* s_out_w = (const float*)d_in[13];
  const float* t_in_w  = (const float*)d_in[14];
  const float* t_conv_w= (const float*)d_in[15];
  const float* t_conv_b= (const float*)d_in[16];
  const float* t_kln_g = (const float*)d_in[17];
  const float* t_kln_b = (const float*)d_in[18];
  const float* t_k_w   = (const float*)d_in[19];
  const float* t_k_b   = (const float*)d_in[20];
  const float* t_qln_g = (const float*)d_in[21];
  const float* t_qln_b = (const float*)d_in[22];
  const float* t_q_w   = (const float*)d_in[23];
  const float* t_q_b   = (const float*)d_in[24];
  const float* t_dtbc_w= (const float*)d_in[25];
  const float* t_dt_w  = (const float*)d_in[26];
  const float* t_dt_b  = (const float*)d_in[27];
  const float* t_gate_w= (const float*)d_in[28];
  const float* t_gate_b= (const float*)d_in[29];
  const float* t_Alog  = (const float*)d_in[30];
  const float* t_D     = (const float*)d_in[31];
  const float* t_out_w = (const float*)d_in[32];

  float* out1 = (float*)d_out;               // (4, 96, 4096)
  float* out2 = out1 + (size_t)4 * 96 * L;   // (4, 288, 4096) = 4,718,592 f
  float* ws = (float*)d_ws;

  // Weights (bf16) — sizes in float units = (u16 count)/2
  u16* w_sin   = (u16*)(ws + 0);        // [384][96]   = 18,432 f
  u16* w_sx    = (u16*)(ws + 18432);    // [128][192]  = 12,288 f
  u16* w_sout  = (u16*)(ws + 30720);    // [128][192]  = 12,288 f
  u16* w_tin   = (u16*)(ws + 43008);    // [640][288]  = 92,160 f
  u16* w_tk    = (u16*)(ws + 135168);   // [640][288]
  u16* w_tq    = (u16*)(ws + 227328);   // [640][288]
  u16* w_tdtbc = (u16*)(ws + 319488);   // [128][1152] = 73,728 f
  u16* w_tgate = (u16*)(ws + 393216);   // [640][1152] = 368,640 f
  u16* w_tout  = (u16*)(ws + 761856);   // [384][576]  = 110,592 f -> ends 872,448

  // Activations (u16 [16384][C] = 8192*C floats)
  float* B_ahi  = ws + 872448;    // u16[16384][288] = 2,359,296 f -> 3,231,744
  float* B_aK   = ws + 3231744;   // -> 5,591,040
  float* B_aQ   = ws + 5591040;   // -> 7,950,336
  float* B_all  = ws + 7950336;   // u16[16384][96] = 786,432 f -> 8,736,768
  float* B_xin  = ws + 8736768;   // u16[16384][192] = 1,572,864 f -> 10,309,632
  float* B_zTs  = ws + 10309632;  // -> 11,882,496
  float* B_xc   = ws + 11882496;  // -> 13,455,360
  float* B_xin3 = ws + 13455360;  // u16[16384][576] = 4,718,592 f -> 18,173,952
  float* B_xc3  = ws + 18173952;  // -> 22,892,544
  float* B_kp   = ws + 22892544;  // -> 27,611,136
  float* B_qp   = ws + 27611136;  // -> 32,329,728
  float* B_zg3  = ws + 32329728;  // -> 37,048,320
  float* B_xdbl = ws + 37048320;  // fp32 [16384][64] -> 38,096,896
  float* B_xdbl3= ws + 38096896;  // -> 39,145,472
  float* B_PFs  = ws + 39145472;  // fp32 128*32*768 -> 42,291,200
  // Overlays (liveness-verified):
  float* B_dlt  = B_ahi;          // fp32 16384*192 = 3,145,728 f over a_hi+aK-head (dead after P1)
  float* B_dlt3 = B_kp;           // fp32 16384*576 over kp+qp exactly (dead after P2)
  u16* y_bf = (u16*)B_xin;        // over x_in (dead after conv)
  u16* y3   = (u16*)B_xin3;       // over xin3 (dead after conv)
  float* PFt_a = out2;            // STS PF chunks 0..63: 64*32*2304 = 4,718,592 == |out2|
  float* PFt_b = ws + 4018176;    // STS PF chunks 64..127: dead region [dlt_end, B_xin)
                                  // = aK-tail + aQ + a_ll = 4,718,592 f exactly

  dim3 blk(256);

  // 1) weight conversion
  {
    WAll wa;
    wa.s[0] = {s_in_w,   w_sin,    96, 384, 384};
    wa.s[1] = {s_x_w,    w_sx,    192,  38, 128};
    wa.s[2] = {s_out_w,  w_sout,  192,  96, 128};
    wa.s[3] = {t_in_w,   w_tin,   288, 576, 640};
    wa.s[4] = {t_k_w,    w_tk,    288, 576, 640};
    wa.s[5] = {t_q_w,    w_tq,    288, 576, 640};
    wa.s[6] = {t_dtbc_w, w_tdtbc, 1152, 50, 128};
    wa.s[7] = {t_gate_w, w_tgate, 1152, 576, 640};
    wconv_k<<<dim3(20, 36, 8), blk, 0, stream>>>(wa);
    WAll wb;
    wb.s[0] = {t_out_w,  w_tout,  576, 288, 384};
    wconv_k<<<dim3(12, 18, 1), blk, 0, stream>>>(wb);
  }

  // 2) all four transpose-preps (4 x 512 blocks)
  {
    TPack tp{};
    tp.s[0] = {m_ll,   nullptr, nullptr, zanc,    (u16*)B_all, 96,  0};
    tp.s[1] = {m_high, nullptr, nullptr, nullptr, (u16*)B_ahi, 288, 0};
    tp.s[2] = {Kin,    t_kln_g, t_kln_b, nullptr, (u16*)B_aK,  288, 1};
    tp.s[3] = {Qin,    t_qln_g, t_qln_b, nullptr, (u16*)B_aQ,  288, 1};
    trans_pack_k<<<dim3(2048), blk, 0, stream>>>(tp);
  }

  // 3) P1: s_in + t_in + t_k + t_q (2304 blocks, 128^2 tiles)
  {
    MPack pk{}; pk.nseg = 4;
    pk.starts[0] = 0; pk.starts[1] = 384; pk.starts[2] = 1024; pk.starts[3] = 1664;
    MSeg a{}; a.A0 = (u16*)B_all; a.Wt = w_sin; a.K = 96; a.K1 = 1 << 28; a.Nout = 384;
    a.ldA = 96; a.split = 192; a.outB0 = (u16*)B_xin; a.outB1 = (u16*)B_zTs;
    a.nbx = 3; a.nwg = 384; a.epi = 5; pk.s[0] = a;
    MSeg b{}; b.A0 = (u16*)B_ahi; b.Wt = w_tin; b.K = 288; b.K1 = 1 << 28; b.Nout = 576;
    b.ldA = 288; b.ldo = 576; b.outB0 = (u16*)B_xin3; b.nbx = 5; b.nwg = 640; b.epi = 1; pk.s[1] = b;
    MSeg c{}; c.A0 = (u16*)B_aK; c.Wt = w_tk; c.K = 288; c.K1 = 1 << 28; c.Nout = 576;
    c.ldA = 288; c.ldo = 576; c.bias = t_k_b; c.outB0 = (u16*)B_kp; c.nbx = 5; c.nwg = 640; c.epi = 3; pk.s[2] = c;
    MSeg d{}; d.A0 = (u16*)B_aQ; d.Wt = w_tq; d.K = 288; d.K1 = 1 << 28; d.Nout = 576;
    d.ldA = 288; d.ldo = 576; d.bias = t_q_b; d.outB0 = (u16*)B_qp; d.nbx = 5; d.nwg = 640; d.epi = 3; pk.s[3] = d;
    mfma_pack_k<<<dim3(2304), blk, 0, stream>>>(pk);
  }

  // 4) both convs (1536 + 4608 blocks)
  {
    CPack cp{}; cp.start1 = 1536;
    cp.s[0] = {(u16*)B_xin,  s_conv_w, s_conv_b, (u16*)B_xc,  192, 3};
    cp.s[1] = {(u16*)B_xin3, t_conv_w, t_conv_b, (u16*)B_xc3, 576, 9};
    conv_pack_k<<<dim3(6144), blk, 0, stream>>>(cp);
  }

  // 5) P2: s_x + dtbc + gate (128 + 128 + 640 = 896 blocks)
  {
    MPack pk{}; pk.nseg = 3;
    pk.starts[0] = 0; pk.starts[1] = 128; pk.starts[2] = 256; pk.starts[3] = 896;
    MSeg a{}; a.A0 = (u16*)B_xc; a.Wt = w_sx; a.K = 192; a.K1 = 1 << 28; a.Nout = 64;
    a.ldA = 192; a.ldo = 64; a.outF = B_xdbl; a.nbx = 1; a.nwg = 128; a.epi = 0; pk.s[0] = a;
    MSeg b{}; b.A0 = (u16*)B_xc3; b.A1 = (u16*)B_kp; b.Wt = w_tdtbc; b.K = 1152; b.K1 = 576;
    b.Nout = 64; b.ldA = 576; b.ldo = 64; b.outF = B_xdbl3; b.nbx = 1; b.nwg = 128; b.epi = 0; pk.s[1] = b;
    MSeg c{}; c.A0 = (u16*)B_xc3; c.A1 = (u16*)B_qp; c.Wt = w_tgate; c.K = 1152; c.K1 = 576;
    c.Nout = 576; c.ldA = 576; c.ldo = 576; c.bias = t_gate_b; c.outB0 = (u16*)B_zg3;
    c.nbx = 5; c.nwg = 640; c.epi = 4; pk.s[2] = c;
    mfma_pack_k<<<dim3(896), blk, 0, stream>>>(pk);
  }

  // 6) both dt-projection fp32 GEMMs (768 + 2304 blocks)
  {
    FPack fp{}; fp.start1 = 768;
    fp.s[0] = {B_xdbl,  s_dt_w, s_dt_b, B_dlt,  6,  192, 64, 192, 3};
    fp.s[1] = {B_xdbl3, t_dt_w, t_dt_b, B_dlt3, 18, 576, 64, 576, 9};
    gemm_f32_pack_k<<<dim3(3072), blk, 0, stream>>>(fp);
  }

  // 7-9) scans + stitch. SSS: CLen=32, 4x128x1 = 512 blocks (single PF).
  //      STS: CLen=32 (was 64), NC=128, 4x128x3 = 1536 blocks, split PF
  //      (chunks 0..63 -> out2, 64..127 -> dead prep region).
  S3Pack sp{}; sp.start1 = 512;
  sp.s[0] = {(u16*)B_xc,  B_dlt,  s_Alog, B_xdbl,  s_D, (u16*)B_zTs, B_PFs, B_PFs, y_bf, 6,  192, 32, 768,  1, 128};
  sp.s[1] = {(u16*)B_xc3, B_dlt3, t_Alog, B_xdbl3, t_D, (u16*)B_zg3, PFt_a, PFt_b, y3,   18, 576, 32, 2304, 3, 64};
  scan3_pack_k<1><<<dim3(2048), blk, 0, stream>>>(sp);
  stitch_pack_k<<<dim3(192), blk, 0, stream>>>(
      B_PFs, B_PFs, 128, 128, 768, 12288,
      PFt_a, PFt_b, 64, 128, 2304, 36864);
  scan3_pack_k<3><<<dim3(2048), blk, 0, stream>>>(sp);

  // 10) P3: s_out + t_out (128 + 384 = 512 blocks)
  {
    MPack pk{}; pk.nseg = 2;
    pk.starts[0] = 0; pk.starts[1] = 128; pk.starts[2] = 512; pk.starts[3] = 512;
    MSeg a{}; a.A0 = y_bf; a.Wt = w_sout; a.K = 192; a.K1 = 1 << 28; a.Nout = 96;
    a.ldA = 192; a.res = m_ll; a.outF = out1; a.nbx = 1; a.nwg = 128; a.epi = 2; pk.s[0] = a;
    MSeg b{}; b.A0 = y3; b.Wt = w_tout; b.K = 576; b.K1 = 1 << 28; b.Nout = 288;
    b.ldA = 576; b.res = m_high; b.outF = out2; b.nbx = 3; b.nwg = 384; b.epi = 2; pk.s[1] = b;
    mfma_pack_k<<<dim3(512), blk, 0, stream>>>(pk);
  }
}